// Round 5
// baseline (1393.230 us; speedup 1.0000x reference)
//
#include <hip/hip_runtime.h>
#include <hip/hip_bf16.h>

// ---------------------------------------------------------------------------
// TransformerSquared forward on MI355X.
// R4: logits GEMM -> 256x256 K-slice-ring kernel (counted vmcnt(8), raw
// s_barrier, ring of 4 x 32-K slices in LDS, 8 waves). attn softmax in exp2.
// ---------------------------------------------------------------------------

#define T_SEQ 2048
#define DMODEL 1024
#define NHEAD 16
#define HSZ 64
#define NLAYER 4
#define FFDIM 4096
#define RH 16
#define RP 256
#define RF 256
#define VOCAB 32000
#define NKQV (3 * NHEAD * RH) // 768

typedef short short8 __attribute__((ext_vector_type(8)));
typedef float f32x4 __attribute__((ext_vector_type(4)));
typedef unsigned int uint_t;
typedef unsigned short ushort_t;

__device__ __forceinline__ float bfbits2f(uint_t bits16_in_low) {
    uint_t b = bits16_in_low << 16;
    float f;
    __builtin_memcpy(&f, &b, 4);
    return f;
}
__device__ __forceinline__ ushort_t f2bfu(float f) {
    union { __hip_bfloat16 b; ushort_t u; } cv;
    cv.b = __float2bfloat16(f);
    return cv.u;
}
__device__ __forceinline__ uint_t pack2bf(float a, float b) {
    return (uint_t)f2bfu(a) | ((uint_t)f2bfu(b) << 16);
}

// async global->LDS, 16 bytes per lane. LDS dest = wave-uniform base + lane*16.
__device__ __forceinline__ void gld16(const __hip_bfloat16* g, short* l) {
    __builtin_amdgcn_global_load_lds(
        (const __attribute__((address_space(1))) void*)g,
        (__attribute__((address_space(3))) void*)l, 16, 0, 0);
}

// ------------------------------- f32 -> bf16 -------------------------------
__global__ __launch_bounds__(256) void cvt_k(const float* __restrict__ in,
                                             __hip_bfloat16* __restrict__ out, int n4) {
    int i = blockIdx.x * 256 + threadIdx.x;
    if (i >= n4) return;
    float4 v = ((const float4*)in)[i];
    ushort4 o;
    o.x = f2bfu(v.x); o.y = f2bfu(v.y); o.z = f2bfu(v.z); o.w = f2bfu(v.w);
    ((ushort4*)out)[i] = o;
}

// ------------------------------- embedding ---------------------------------
__global__ __launch_bounds__(256) void embed_k(const int* __restrict__ idx,
                                               const float* __restrict__ tok,
                                               const float* __restrict__ pos,
                                               float* __restrict__ x) {
    int i = blockIdx.x * 256 + threadIdx.x;          // over T*D/4
    int d4 = i & (DMODEL / 4 - 1);
    int t = i >> 8;                                   // D/4 = 256
    int tk = idx[t];
    float4 a = ((const float4*)(tok + (size_t)tk * DMODEL))[d4];
    float4 p = ((const float4*)(pos + (size_t)t * DMODEL))[d4];
    a.x += p.x; a.y += p.y; a.z += p.z; a.w += p.w;
    ((float4*)(x + (size_t)t * DMODEL))[d4] = a;
}

// ------------------------------- layernorm ---------------------------------
__global__ __launch_bounds__(256) void ln_k(const float* __restrict__ xin,
                                            const float* __restrict__ w,
                                            const float* __restrict__ b,
                                            __hip_bfloat16* __restrict__ out) {
    const int row = blockIdx.x, tid = threadIdx.x;
    const float4 v = ((const float4*)(xin + (size_t)row * DMODEL))[tid];
    float s = v.x + v.y + v.z + v.w;
    float q = v.x * v.x + v.y * v.y + v.z * v.z + v.w * v.w;
    for (int off = 32; off; off >>= 1) { s += __shfl_xor(s, off); q += __shfl_xor(q, off); }
    __shared__ float rs_[4], rq_[4];
    if ((tid & 63) == 0) { rs_[tid >> 6] = s; rq_[tid >> 6] = q; }
    __syncthreads();
    s = rs_[0] + rs_[1] + rs_[2] + rs_[3];
    q = rq_[0] + rq_[1] + rq_[2] + rq_[3];
    const float mean = s * (1.f / DMODEL);
    const float var = q * (1.f / DMODEL) - mean * mean;
    const float rstd = rsqrtf(var + 1e-5f);
    const float4 wv = ((const float4*)w)[tid];
    const float4 bv = ((const float4*)b)[tid];
    ushort4 o;
    o.x = f2bfu((v.x - mean) * rstd * wv.x + bv.x);
    o.y = f2bfu((v.y - mean) * rstd * wv.y + bv.y);
    o.z = f2bfu((v.z - mean) * rstd * wv.z + bv.z);
    o.w = f2bfu((v.w - mean) * rstd * wv.w + bv.w);
    ((ushort4*)out)[(size_t)row * (DMODEL / 4) + tid] = o;
}

// --------------------------- generic GEMM (A * B^T) ------------------------
// m97-structure, 2-barrier. Used for everything except the logits GEMM.
template <int BM, int BN, int MODE>
__global__ __launch_bounds__(256) void gemm_t(const __hip_bfloat16* __restrict__ A,
                                              const __hip_bfloat16* __restrict__ B,
                                              const float* __restrict__ colscale,
                                              __hip_bfloat16* __restrict__ Cb,
                                              float* __restrict__ Cf,
                                              int M, int N, int K) {
    constexpr int WM = (BN >= 128) ? 2 : 4;
    constexpr int WN = 4 / WM;
    constexpr int TM = BM / WM / 16;
    constexpr int TN = BN / WN / 16;
    constexpr int IA = BM / 32;     // gld16 iters for A tile
    constexpr int IB = BN / 32;
    __shared__ short As[BM * 64];
    __shared__ short Bs[BN * 64];
    const int tid = threadIdx.x;
    const int w = tid >> 6, ln = tid & 63, lr = ln & 15, lg = ln >> 4;
    const int GM = M / BM;

    const int nwg = gridDim.x;
    const int cpx = nwg >> 3;
    const int wg = (blockIdx.x & 7) * cpx + (blockIdx.x >> 3);
    const int bm = wg % GM, bn = wg / GM;
    const int wm = w / WN, wn = w % WN;

    f32x4 acc[TM][TN] = {};

    const int srow = tid >> 3;
    const int scol = (((tid & 7) ^ ((tid >> 3) & 7)) * 8);
    const __hip_bfloat16* Ag = A + (size_t)(bm * BM + srow) * K + scol;
    const __hip_bfloat16* Bg = B + (size_t)(bn * BN + srow) * K + scol;

    for (int kt = 0; kt < K; kt += 64) {
        __syncthreads();   // previous tile consumed
#pragma unroll
        for (int i = 0; i < IA; ++i)
            gld16(Ag + (size_t)(i * 32) * K + kt, &As[i * 2048 + w * 512]);
#pragma unroll
        for (int i = 0; i < IB; ++i)
            gld16(Bg + (size_t)(i * 32) * K + kt, &Bs[i * 2048 + w * 512]);
        __syncthreads();   // drains vmcnt + barrier

#pragma unroll
        for (int kk = 0; kk < 2; ++kk) {
            short8 af[TM], bf[TN];
#pragma unroll
            for (int m = 0; m < TM; ++m) {
                const int row = wm * (BM / WM) + m * 16 + lr;
                af[m] = *(const short8*)&As[row * 64 + (((kk * 4 + lg) ^ (lr & 7)) * 8)];
            }
#pragma unroll
            for (int n = 0; n < TN; ++n) {
                const int row = wn * (BN / WN) + n * 16 + lr;
                bf[n] = *(const short8*)&Bs[row * 64 + (((kk * 4 + lg) ^ (lr & 7)) * 8)];
            }
#pragma unroll
            for (int m = 0; m < TM; ++m)
#pragma unroll
                for (int n = 0; n < TN; ++n)
                    acc[m][n] = __builtin_amdgcn_mfma_f32_16x16x32_bf16(af[m], bf[n], acc[m][n], 0, 0, 0);
        }
    }

#pragma unroll
    for (int n = 0; n < TN; ++n) {
        const int col = bn * BN + wn * (BN / WN) + n * 16 + lr;
        float cs = 1.0f;
        if (MODE == 0 && colscale) cs = colscale[col];
#pragma unroll
        for (int m = 0; m < TM; ++m) {
#pragma unroll
            for (int rr = 0; rr < 4; ++rr) {
                const int row = bm * BM + wm * (BM / WM) + m * 16 + lg * 4 + rr;
                float v = acc[m][n][rr];
                const size_t o = (size_t)row * N + col;
                if (MODE == 0) {
                    Cb[o] = __float2bfloat16(v * cs);
                } else if (MODE == 1) {
                    v = 0.5f * v * (1.0f + erff(v * 0.70710678118654752f));
                    Cb[o] = __float2bfloat16(v);
                } else if (MODE == 2) {
                    Cf[o] += v;
                } else {
                    Cf[o] = v;
                }
            }
        }
    }
}

// ----------------- 256x256 K-slice-ring GEMM (logits, f32 out) -------------
// C = A[M,K] * B[N,K]^T. 512 threads = 8 waves (2 wm x 4 wn), each wave owns
// a 128x64 output. K sliced into 32-wide slices; LDS ring of 4 slice-buffers
// per operand (128 KiB total). Stage slice s+3 while computing slice s;
// one raw s_barrier + counted vmcnt(8) per slice (no drain in main loop).
__global__ __launch_bounds__(512, 2) void gemm256_k(const __hip_bfloat16* __restrict__ A,
                                                    const __hip_bfloat16* __restrict__ B,
                                                    float* __restrict__ C,
                                                    int M, int N, int K) {
    __shared__ short Ar[4][256 * 32];
    __shared__ short Br[4][256 * 32];
    const int tid = threadIdx.x;
    const int w = tid >> 6, ln = tid & 63, lr = ln & 15, lg = ln >> 4;
    const int wm = w >> 2, wn = w & 3;
    const int GM = M / 256;

    const int nwg = gridDim.x;
    const int cpx = nwg >> 3;
    const int wg = (blockIdx.x & 7) * cpx + (blockIdx.x >> 3);
    const int bm = wg % GM, bn = wg / GM;

    // staging: slice = 256 rows x 32 cols bf16 (64 B/row, 4 x 16B units).
    // 2 gld16 per operand-slice; load j covers rows j*128 + (tid>>2).
    // LDS is linear; source unit pre-swizzled: g = (tid&3) ^ swz(row),
    // swz(row) = (row&3) ^ ((row>>2)&3)  [== ((ln>>2)&3) ^ ((ln>>4)&3)].
    const int srow = tid >> 2;                        // 0..127
    const int g0 = (tid & 3) ^ ((srow & 3) ^ ((srow >> 2) & 3));
    const __hip_bfloat16* Ag = A + (size_t)(bm * 256 + srow) * K + g0 * 8;
    const __hip_bfloat16* Bg = B + (size_t)(bn * 256 + srow) * K + g0 * 8;
    const size_t rowK128 = (size_t)128 * K;
    const int ldsbase = w * 16 * 32;                  // shorts; wave-uniform

    f32x4 acc[8][4] = {};

    const int S = K / 32;                             // 32 slices for K=1024
    auto STAGE = [&](int s) {
        const int rb = s & 3;
        const size_t ko = (size_t)s * 32;
        gld16(Ag + ko,           &Ar[rb][ldsbase]);
        gld16(Ag + ko + rowK128, &Ar[rb][128 * 32 + ldsbase]);
        gld16(Bg + ko,           &Br[rb][ldsbase]);
        gld16(Bg + ko + rowK128, &Br[rb][128 * 32 + ldsbase]);
    };

    STAGE(0); STAGE(1); STAGE(2);                     // 12 vmem instr / wave

    const int uX = (lg ^ ((lr & 3) ^ ((lr >> 2) & 3))) * 8;  // swizzled unit
    const int arow0 = wm * 128 + lr;
    const int brow0 = wn * 64 + lr;

    for (int s = 0; s < S; ++s) {
        if (s < S - 2)       asm volatile("s_waitcnt vmcnt(8)" ::: "memory");
        else if (s == S - 2) asm volatile("s_waitcnt vmcnt(4)" ::: "memory");
        else                 asm volatile("s_waitcnt vmcnt(0)" ::: "memory");
        __builtin_amdgcn_s_barrier();
        __builtin_amdgcn_sched_barrier(0);
        if (s + 3 < S) STAGE(s + 3);

        const int rb = s & 3;
        const short* Ab = Ar[rb];
        const short* Bb = Br[rb];
        short8 af[8], bf[4];
#pragma unroll
        for (int m = 0; m < 8; ++m)
            af[m] = *(const short8*)&Ab[(arow0 + m * 16) * 32 + uX];
#pragma unroll
        for (int n = 0; n < 4; ++n)
            bf[n] = *(const short8*)&Bb[(brow0 + n * 16) * 32 + uX];
        asm volatile("s_waitcnt lgkmcnt(0)" ::: "memory");
        __builtin_amdgcn_sched_barrier(0);
        __builtin_amdgcn_s_setprio(1);
#pragma unroll
        for (int m = 0; m < 8; ++m)
#pragma unroll
            for (int n = 0; n < 4; ++n)
                acc[m][n] = __builtin_amdgcn_mfma_f32_16x16x32_bf16(af[m], bf[n], acc[m][n], 0, 0, 0);
        __builtin_amdgcn_s_setprio(0);
    }

#pragma unroll
    for (int n = 0; n < 4; ++n) {
        const int col = bn * 256 + wn * 64 + n * 16 + lr;
#pragma unroll
        for (int m = 0; m < 8; ++m) {
#pragma unroll
            for (int rr = 0; rr < 4; ++rr) {
                const int row = bm * 256 + wm * 128 + m * 16 + lg * 4 + rr;
                C[(size_t)row * N + col] = acc[m][n][rr];
            }
        }
    }
}

// ----------------------- per-head SVF U-projection (K=16) ------------------
__global__ __launch_bounds__(256) void kqv2_k(const __hip_bfloat16* __restrict__ t1,
                                              const __hip_bfloat16* __restrict__ U,
                                              __hip_bfloat16* __restrict__ kqv) {
    size_t i = (size_t)blockIdx.x * 256 + threadIdx.x; // 3*16*2048*64
    int s = (int)(i & 63);
    size_t rest = i >> 6;
    int t = (int)(rest & (T_SEQ - 1));
    int gh = (int)(rest >> 11);
    const short8* trow = (const short8*)(t1 + (size_t)t * NKQV + gh * RH);
    const short8* urow = (const short8*)(U + ((size_t)gh * HSZ + s) * RH);
    short8 ta = trow[0], tb = trow[1];
    short8 ua = urow[0], ub = urow[1];
    float acc = 0.f;
#pragma unroll
    for (int j = 0; j < 8; ++j) {
        acc += bfbits2f((ushort_t)ta[j]) * bfbits2f((ushort_t)ua[j]);
        acc += bfbits2f((ushort_t)tb[j]) * bfbits2f((ushort_t)ub[j]);
    }
    kqv[i] = __float2bfloat16(acc);
}

// --------------------------- V transpose per head --------------------------
__global__ __launch_bounds__(256) void vtrans_k(const __hip_bfloat16* __restrict__ vb,
                                                __hip_bfloat16* __restrict__ vt) {
    __shared__ short Ts[64][72];
    const int ti = blockIdx.x, h = blockIdx.y, tid = threadIdx.x;
    const int tl = tid >> 2, sc = (tid & 3) * 16;
    const short* src = (const short*)(vb + ((size_t)h * T_SEQ + ti * 64 + tl) * HSZ + sc);
    short8 a = ((const short8*)src)[0];
    short8 b = ((const short8*)src)[1];
#pragma unroll
    for (int j = 0; j < 8; ++j) { Ts[sc + j][tl] = a[j]; Ts[sc + 8 + j][tl] = b[j]; }
    __syncthreads();
    const int s = tid >> 2;
    short8 o0, o1;
#pragma unroll
    for (int j = 0; j < 8; ++j) { o0[j] = Ts[s][sc + j]; o1[j] = Ts[s][sc + 8 + j]; }
    short* dst = (short*)(vt + ((size_t)h * HSZ + s) * T_SEQ + ti * 64 + sc);
    ((short8*)dst)[0] = o0;
    ((short8*)dst)[1] = o1;
}

// --------------------------- MFMA flash attention --------------------------
// 1 wave = 16 q rows, KVBLK = 64. Softmax in exp2 domain.
__global__ __launch_bounds__(256) void attn_k(const __hip_bfloat16* __restrict__ qb,
                                              const __hip_bfloat16* __restrict__ kb,
                                              const __hip_bfloat16* __restrict__ vtb,
                                              __hip_bfloat16* __restrict__ attout) {
    __shared__ short P_s[2][4][16 * 72];  // [dbuf][wave][16 q x 64 u], stride 72
    const int tid = threadIdx.x, w = tid >> 6, ln = tid & 63;
    const int lr = ln & 15, lg = ln >> 4;
    const int h = blockIdx.y;
    const int t0 = blockIdx.x * 16 + w * 512;
    const size_t hb = (size_t)h * T_SEQ;
    const size_t vtbase = (size_t)h * HSZ * T_SEQ;
    const float SCL = 0.18033688011112042f; // 0.125 * log2(e)

    short8 qf0 = *(const short8*)(qb + (hb + t0 + lr) * HSZ + lg * 8);
    short8 qf1 = *(const short8*)(qb + (hb + t0 + lr) * HSZ + 32 + lg * 8);

    f32x4 acc[4] = {};
    float mrun = -3e38f, lrun = 0.f;
    int pbuf = 0;

    short8 kf[4][2];
#pragma unroll
    for (int g = 0; g < 4; ++g) {
        kf[g][0] = *(const short8*)(kb + (hb + g * 16 + lr) * HSZ + lg * 8);
        kf[g][1] = *(const short8*)(kb + (hb + g * 16 + lr) * HSZ + 32 + lg * 8);
    }

    for (int u0 = 0; u0 <= t0 + 15; u0 += 64) {
        f32x4 st[4];
#pragma unroll
        for (int g = 0; g < 4; ++g) {
            f32x4 z = {};
            z = __builtin_amdgcn_mfma_f32_16x16x32_bf16(kf[g][0], qf0, z, 0, 0, 0);
            st[g] = __builtin_amdgcn_mfma_f32_16x16x32_bf16(kf[g][1], qf1, z, 0, 0, 0);
        }

        const int un = u0 + 64;
        if (un <= t0 + 15) {
#pragma unroll
            for (int g = 0; g < 4; ++g) {
                kf[g][0] = *(const short8*)(kb + (hb + un + g * 16 + lr) * HSZ + lg * 8);
                kf[g][1] = *(const short8*)(kb + (hb + un + g * 16 + lr) * HSZ + 32 + lg * 8);
            }
        }
        short8 vf[4][2];
#pragma unroll
        for (int dt = 0; dt < 4; ++dt) {
            vf[dt][0] = *(const short8*)(vtb + vtbase + (size_t)(dt * 16 + lr) * T_SEQ + u0 + lg * 8);
            vf[dt][1] = *(const short8*)(vtb + vtbase + (size_t)(dt * 16 + lr) * T_SEQ + u0 + 32 + lg * 8);
        }

        const int qg = t0 + lr;
        float sv[16];
#pragma unroll
        for (int g = 0; g < 4; ++g) {
            const bool needm = (u0 + g * 16 + 15 > t0);
#pragma unroll
            for (int r = 0; r < 4; ++r) {
                float v = st[g][r] * SCL;
                if (needm && (u0 + g * 16 + lg * 4 + r > qg)) v = -1e30f;
                sv[g * 4 + r] = v;
            }
        }
        float tm = sv[0];
#pragma unroll
        for (int j = 1; j < 16; ++j) tm = fmaxf(tm, sv[j]);
        tm = fmaxf(tm, __shfl_xor(tm, 16));
        tm = fmaxf(tm, __shfl_xor(tm, 32));
        const float mnew = fmaxf(mrun, tm);
        const float corr = exp2f(mrun - mnew);
        float pv[16];
        float ls = 0.f;
#pragma unroll
        for (int j = 0; j < 16; ++j) { pv[j] = exp2f(sv[j] - mnew); ls += pv[j]; }
        ls += __shfl_xor(ls, 16);
        ls += __shfl_xor(ls, 32);
        lrun = lrun * corr + ls;
#pragma unroll
        for (int dt = 0; dt < 4; ++dt) acc[dt] *= corr;

        uint_t* pw = (uint_t*)P_s[pbuf][w];
        const int wb = lr * 36 + lg * 2;
#pragma unroll
        for (int g = 0; g < 4; ++g) {
            pw[wb + g * 8 + 0] = pack2bf(pv[g * 4 + 0], pv[g * 4 + 1]);
            pw[wb + g * 8 + 1] = pack2bf(pv[g * 4 + 2], pv[g * 4 + 3]);
        }
        asm volatile("s_waitcnt lgkmcnt(0)" ::: "memory");
        short8 pf0 = *(const short8*)(&P_s[pbuf][w][lr * 72 + lg * 8]);
        short8 pf1 = *(const short8*)(&P_s[pbuf][w][lr * 72 + 32 + lg * 8]);

#pragma unroll
        for (int dt = 0; dt < 4; ++dt) {
            acc[dt] = __builtin_amdgcn_mfma_f32_16x16x32_bf16(vf[dt][0], pf0, acc[dt], 0, 0, 0);
            acc[dt] = __builtin_amdgcn_mfma_f32_16x16x32_bf16(vf[dt][1], pf1, acc[dt], 0, 0, 0);
        }

        mrun = mnew;
        pbuf ^= 1;
    }

    const float inv = 1.f / lrun;
#pragma unroll
    for (int dt = 0; dt < 4; ++dt) {
#pragma unroll
        for (int r = 0; r < 4; r += 2) {
            uint_t pk = pack2bf(acc[dt][r] * inv, acc[dt][r + 1] * inv);
            *(uint_t*)(attout + (size_t)(t0 + lr) * DMODEL + h * HSZ + dt * 16 + lg * 4 + r) = pk;
        }
    }
}

// ---------------------------------------------------------------------------
extern "C" void kernel_launch(void* const* d_in, const int* in_sizes, int n_in,
                              void* d_out, int out_size, void* d_ws, size_t ws_size,
                              hipStream_t stream) {
    const int* idx = (const int*)d_in[0];
    const float* tok_emb = (const float*)d_in[1];
    const float* pos_emb = (const float*)d_in[2];
    const float* ln1_w = (const float*)d_in[3];
    const float* ln1_b = (const float*)d_in[4];
    const float* ln2_w = (const float*)d_in[5];
    const float* ln2_b = (const float*)d_in[6];
    const float* kqv_V = (const float*)d_in[7];
    const float* kqv_z = (const float*)d_in[8];
    const float* kqv_U = (const float*)d_in[9];
    const float* proj_V = (const float*)d_in[10];
    const float* proj_z = (const float*)d_in[11];
    const float* proj_U = (const float*)d_in[12];
    const float* f1_V = (const float*)d_in[13];
    const float* f1_z = (const float*)d_in[14];
    const float* f1_U = (const float*)d_in[15];
    const float* f2_V = (const float*)d_in[16];
    const float* f2_z = (const float*)d_in[17];
    const float* f2_U = (const float*)d_in[18];
    const float* lnf_w = (const float*)d_in[19];
    const float* lnf_b = (const float*)d_in[20];
    const float* lm_w = (const float*)d_in[21];

    // ---------------- workspace layout ----------------
    char* W = (char*)d_ws;
    float* x = (float*)W;                 W += (size_t)T_SEQ * DMODEL * 4;
    __hip_bfloat16* hbuf = (__hip_bfloat16*)W; W += (size_t)T_SEQ * DMODEL * 2;
    __hip_bfloat16* t1 = (__hip_bfloat16*)W;   W += (size_t)T_SEQ * NKQV * 2;
    __hip_bfloat16* kqvb = (__hip_bfloat16*)W; W += (size_t)3 * NHEAD * T_SEQ * HSZ * 2;
    __hip_bfloat16* vtb = (__hip_bfloat16*)W;  W += (size_t)NHEAD * HSZ * T_SEQ * 2;
    __hip_bfloat16* attb = (__hip_bfloat16*)W; W += (size_t)T_SEQ * DMODEL * 2;
    __hip_bfloat16* ffb = (__hip_bfloat16*)W;  W += (size_t)T_SEQ * FFDIM * 2;
    __hip_bfloat16* wkV = (__hip_bfloat16*)W;  W += (size_t)NLAYER * NKQV * DMODEL * 2;
    __hip_bfloat16* wkU = (__hip_bfloat16*)W;  W += (size_t)NLAYER * 3 * NHEAD * HSZ * RH * 2;
    __hip_bfloat16* wpV = (__hip_bfloat16*)W;  W += (size_t)NLAYER * RP * DMODEL * 2;
    __hip_bfloat16* wpU = (__hip_bfloat16*)W;  W += (size_t)NLAYER * DMODEL * RP * 2;
    __hip_bfloat16* w1V = (__hip_bfloat16*)W;  W += (size_t)NLAYER * RF * DMODEL * 2;
    __hip_bfloat16* w1U = (__hip_bfloat16*)W;  W += (size_t)NLAYER * FFDIM * RF * 2;
    __hip_bfloat16* w2V = (__hip_bfloat16*)W;  W += (size_t)NLAYER * RF * FFDIM * 2;
    __hip_bfloat16* w2U = (__hip_bfloat16*)W;  W += (size_t)NLAYER * DMODEL * RF * 2;
    __hip_bfloat16* wlm = (__hip_bfloat16*)W;  W += (size_t)VOCAB * DMODEL * 2;

    auto cvt = [&](const float* src, __hip_bfloat16* dst, size_t n) {
        int n4 = (int)(n / 4);
        cvt_k<<<dim3((n4 + 255) / 256), dim3(256), 0, stream>>>(src, dst, n4);
    };
    cvt(kqv_V, wkV, (size_t)NLAYER * NKQV * DMODEL);
    cvt(kqv_U, wkU, (size_t)NLAYER * 3 * NHEAD * HSZ * RH);
    cvt(proj_V, wpV, (size_t)NLAYER * RP * DMODEL);
    cvt(proj_U, wpU, (size_t)NLAYER * DMODEL * RP);
    cvt(f1_V, w1V, (size_t)NLAYER * RF * DMODEL);
    cvt(f1_U, w1U, (size_t)NLAYER * FFDIM * RF);
    cvt(f2_V, w2V, (size_t)NLAYER * RF * FFDIM);
    cvt(f2_U, w2U, (size_t)NLAYER * DMODEL * RF);
    cvt(lm_w, wlm, (size_t)VOCAB * DMODEL);

    embed_k<<<dim3(T_SEQ * DMODEL / 4 / 256), dim3(256), 0, stream>>>(idx, tok_emb, pos_emb, x);

    const int M = T_SEQ;
    for (int l = 0; l < NLAYER; ++l) {
        ln_k<<<dim3(T_SEQ), dim3(256), 0, stream>>>(x, ln1_w + l * DMODEL, ln1_b + l * DMODEL, hbuf);
        gemm_t<64, 64, 0><<<dim3((M / 64) * (NKQV / 64)), dim3(256), 0, stream>>>(
            hbuf, wkV + (size_t)l * NKQV * DMODEL, kqv_z + (size_t)l * NKQV,
            t1, nullptr, M, NKQV, DMODEL);
        kqv2_k<<<dim3(3 * NHEAD * T_SEQ * HSZ / 256), dim3(256), 0, stream>>>(
            t1, wkU + (size_t)l * 3 * NHEAD * HSZ * RH, kqvb);
        {
            const __hip_bfloat16* kk = kqvb;
            const __hip_bfloat16* qq = kqvb + (size_t)NHEAD * T_SEQ * HSZ;
            const __hip_bfloat16* vv = kqvb + (size_t)2 * NHEAD * T_SEQ * HSZ;
            vtrans_k<<<dim3(T_SEQ / 64, NHEAD), dim3(256), 0, stream>>>(vv, vtb);
            attn_k<<<dim3(T_SEQ / 64, NHEAD), dim3(256), 0, stream>>>(qq, kk, vtb, attb);
        }
        gemm_t<64, 64, 0><<<dim3((M / 64) * (RP / 64)), dim3(256), 0, stream>>>(
            attb, wpV + (size_t)l * RP * DMODEL, proj_z + (size_t)l * RP,
            t1, nullptr, M, RP, DMODEL);
        gemm_t<128, 128, 2><<<dim3((M / 128) * (DMODEL / 128)), dim3(256), 0, stream>>>(
            t1, wpU + (size_t)l * DMODEL * RP, nullptr,
            nullptr, x, M, DMODEL, RP);
        ln_k<<<dim3(T_SEQ), dim3(256), 0, stream>>>(x, ln2_w + l * DMODEL, ln2_b + l * DMODEL, hbuf);
        gemm_t<64, 64, 0><<<dim3((M / 64) * (RF / 64)), dim3(256), 0, stream>>>(
            hbuf, w1V + (size_t)l * RF * DMODEL, f1_z + (size_t)l * RF,
            t1, nullptr, M, RF, DMODEL);
        gemm_t<128, 128, 1><<<dim3((M / 128) * (FFDIM / 128)), dim3(256), 0, stream>>>(
            t1, w1U + (size_t)l * FFDIM * RF, nullptr,
            ffb, nullptr, M, FFDIM, RF);
        gemm_t<64, 64, 0><<<dim3((M / 64) * (RF / 64)), dim3(256), 0, stream>>>(
            ffb, w2V + (size_t)l * RF * FFDIM, f2_z + (size_t)l * RF,
            t1, nullptr, M, RF, FFDIM);
        gemm_t<128, 128, 2><<<dim3((M / 128) * (DMODEL / 128)), dim3(256), 0, stream>>>(
            t1, w2U + (size_t)l * DMODEL * RF, nullptr,
            nullptr, x, M, DMODEL, RF);
    }
    ln_k<<<dim3(T_SEQ), dim3(256), 0, stream>>>(x, lnf_w, lnf_b, hbuf);
    // logits: 256x256 K-slice-ring kernel, grid 8*125 = 1000 (div by 8)
    gemm256_k<<<dim3((M / 256) * (VOCAB / 256)), dim3(512), 0, stream>>>(
        hbuf, wlm, (float*)d_out, M, VOCAB, DMODEL);
}

// Round 6
// 1359.447 us; speedup vs baseline: 1.0249x; 1.0249x over previous
//
#include <hip/hip_runtime.h>
#include <hip/hip_bf16.h>

// ---------------------------------------------------------------------------
// TransformerSquared forward on MI355X.
// R5: logits reverted to proven gemm_t<128,128>. Attention -> causal
// key-split flash (partials over <=512-key ranges + combine kernel),
// raising attn occupancy 2 -> ~5 blocks/CU. Partial buffers overlaid on ffb.
// ---------------------------------------------------------------------------

#define T_SEQ 2048
#define DMODEL 1024
#define NHEAD 16
#define HSZ 64
#define NLAYER 4
#define FFDIM 4096
#define RH 16
#define RP 256
#define RF 256
#define VOCAB 32000
#define NKQV (3 * NHEAD * RH) // 768

typedef short short8 __attribute__((ext_vector_type(8)));
typedef float f32x4 __attribute__((ext_vector_type(4)));
typedef unsigned int uint_t;
typedef unsigned short ushort_t;

__device__ __forceinline__ float bfbits2f(uint_t bits16_in_low) {
    uint_t b = bits16_in_low << 16;
    float f;
    __builtin_memcpy(&f, &b, 4);
    return f;
}
__device__ __forceinline__ ushort_t f2bfu(float f) {
    union { __hip_bfloat16 b; ushort_t u; } cv;
    cv.b = __float2bfloat16(f);
    return cv.u;
}
__device__ __forceinline__ uint_t pack2bf(float a, float b) {
    return (uint_t)f2bfu(a) | ((uint_t)f2bfu(b) << 16);
}

// async global->LDS, 16 bytes per lane. LDS dest = wave-uniform base + lane*16.
__device__ __forceinline__ void gld16(const __hip_bfloat16* g, short* l) {
    __builtin_amdgcn_global_load_lds(
        (const __attribute__((address_space(1))) void*)g,
        (__attribute__((address_space(3))) void*)l, 16, 0, 0);
}

// ------------------------------- f32 -> bf16 -------------------------------
__global__ __launch_bounds__(256) void cvt_k(const float* __restrict__ in,
                                             __hip_bfloat16* __restrict__ out, int n4) {
    int i = blockIdx.x * 256 + threadIdx.x;
    if (i >= n4) return;
    float4 v = ((const float4*)in)[i];
    ushort4 o;
    o.x = f2bfu(v.x); o.y = f2bfu(v.y); o.z = f2bfu(v.z); o.w = f2bfu(v.w);
    ((ushort4*)out)[i] = o;
}

// ------------------------------- embedding ---------------------------------
__global__ __launch_bounds__(256) void embed_k(const int* __restrict__ idx,
                                               const float* __restrict__ tok,
                                               const float* __restrict__ pos,
                                               float* __restrict__ x) {
    int i = blockIdx.x * 256 + threadIdx.x;          // over T*D/4
    int d4 = i & (DMODEL / 4 - 1);
    int t = i >> 8;                                   // D/4 = 256
    int tk = idx[t];
    float4 a = ((const float4*)(tok + (size_t)tk * DMODEL))[d4];
    float4 p = ((const float4*)(pos + (size_t)t * DMODEL))[d4];
    a.x += p.x; a.y += p.y; a.z += p.z; a.w += p.w;
    ((float4*)(x + (size_t)t * DMODEL))[d4] = a;
}

// ------------------------------- layernorm ---------------------------------
__global__ __launch_bounds__(256) void ln_k(const float* __restrict__ xin,
                                            const float* __restrict__ w,
                                            const float* __restrict__ b,
                                            __hip_bfloat16* __restrict__ out) {
    const int row = blockIdx.x, tid = threadIdx.x;
    const float4 v = ((const float4*)(xin + (size_t)row * DMODEL))[tid];
    float s = v.x + v.y + v.z + v.w;
    float q = v.x * v.x + v.y * v.y + v.z * v.z + v.w * v.w;
    for (int off = 32; off; off >>= 1) { s += __shfl_xor(s, off); q += __shfl_xor(q, off); }
    __shared__ float rs_[4], rq_[4];
    if ((tid & 63) == 0) { rs_[tid >> 6] = s; rq_[tid >> 6] = q; }
    __syncthreads();
    s = rs_[0] + rs_[1] + rs_[2] + rs_[3];
    q = rq_[0] + rq_[1] + rq_[2] + rq_[3];
    const float mean = s * (1.f / DMODEL);
    const float var = q * (1.f / DMODEL) - mean * mean;
    const float rstd = rsqrtf(var + 1e-5f);
    const float4 wv = ((const float4*)w)[tid];
    const float4 bv = ((const float4*)b)[tid];
    ushort4 o;
    o.x = f2bfu((v.x - mean) * rstd * wv.x + bv.x);
    o.y = f2bfu((v.y - mean) * rstd * wv.y + bv.y);
    o.z = f2bfu((v.z - mean) * rstd * wv.z + bv.z);
    o.w = f2bfu((v.w - mean) * rstd * wv.w + bv.w);
    ((ushort4*)out)[(size_t)row * (DMODEL / 4) + tid] = o;
}

// --------------------------- generic GEMM (A * B^T) ------------------------
// m97-structure, 2-barrier, both-sides XOR swizzle (verified 0 conflicts R4).
template <int BM, int BN, int MODE>
__global__ __launch_bounds__(256) void gemm_t(const __hip_bfloat16* __restrict__ A,
                                              const __hip_bfloat16* __restrict__ B,
                                              const float* __restrict__ colscale,
                                              __hip_bfloat16* __restrict__ Cb,
                                              float* __restrict__ Cf,
                                              int M, int N, int K) {
    constexpr int WM = (BN >= 128) ? 2 : 4;
    constexpr int WN = 4 / WM;
    constexpr int TM = BM / WM / 16;
    constexpr int TN = BN / WN / 16;
    constexpr int IA = BM / 32;     // gld16 iters for A tile
    constexpr int IB = BN / 32;
    __shared__ short As[BM * 64];
    __shared__ short Bs[BN * 64];
    const int tid = threadIdx.x;
    const int w = tid >> 6, ln = tid & 63, lr = ln & 15, lg = ln >> 4;
    const int GM = M / BM;

    const int nwg = gridDim.x;
    const int cpx = nwg >> 3;
    const int wg = (blockIdx.x & 7) * cpx + (blockIdx.x >> 3);
    const int bm = wg % GM, bn = wg / GM;
    const int wm = w / WN, wn = w % WN;

    f32x4 acc[TM][TN] = {};

    const int srow = tid >> 3;
    const int scol = (((tid & 7) ^ ((tid >> 3) & 7)) * 8);
    const __hip_bfloat16* Ag = A + (size_t)(bm * BM + srow) * K + scol;
    const __hip_bfloat16* Bg = B + (size_t)(bn * BN + srow) * K + scol;

    for (int kt = 0; kt < K; kt += 64) {
        __syncthreads();   // previous tile consumed
#pragma unroll
        for (int i = 0; i < IA; ++i)
            gld16(Ag + (size_t)(i * 32) * K + kt, &As[i * 2048 + w * 512]);
#pragma unroll
        for (int i = 0; i < IB; ++i)
            gld16(Bg + (size_t)(i * 32) * K + kt, &Bs[i * 2048 + w * 512]);
        __syncthreads();   // drains vmcnt + barrier

#pragma unroll
        for (int kk = 0; kk < 2; ++kk) {
            short8 af[TM], bf[TN];
#pragma unroll
            for (int m = 0; m < TM; ++m) {
                const int row = wm * (BM / WM) + m * 16 + lr;
                af[m] = *(const short8*)&As[row * 64 + (((kk * 4 + lg) ^ (lr & 7)) * 8)];
            }
#pragma unroll
            for (int n = 0; n < TN; ++n) {
                const int row = wn * (BN / WN) + n * 16 + lr;
                bf[n] = *(const short8*)&Bs[row * 64 + (((kk * 4 + lg) ^ (lr & 7)) * 8)];
            }
#pragma unroll
            for (int m = 0; m < TM; ++m)
#pragma unroll
                for (int n = 0; n < TN; ++n)
                    acc[m][n] = __builtin_amdgcn_mfma_f32_16x16x32_bf16(af[m], bf[n], acc[m][n], 0, 0, 0);
        }
    }

#pragma unroll
    for (int n = 0; n < TN; ++n) {
        const int col = bn * BN + wn * (BN / WN) + n * 16 + lr;
        float cs = 1.0f;
        if (MODE == 0 && colscale) cs = colscale[col];
#pragma unroll
        for (int m = 0; m < TM; ++m) {
#pragma unroll
            for (int rr = 0; rr < 4; ++rr) {
                const int row = bm * BM + wm * (BM / WM) + m * 16 + lg * 4 + rr;
                float v = acc[m][n][rr];
                const size_t o = (size_t)row * N + col;
                if (MODE == 0) {
                    Cb[o] = __float2bfloat16(v * cs);
                } else if (MODE == 1) {
                    v = 0.5f * v * (1.0f + erff(v * 0.70710678118654752f));
                    Cb[o] = __float2bfloat16(v);
                } else if (MODE == 2) {
                    Cf[o] += v;
                } else {
                    Cf[o] = v;
                }
            }
        }
    }
}

// ----------------------- per-head SVF U-projection (K=16) ------------------
__global__ __launch_bounds__(256) void kqv2_k(const __hip_bfloat16* __restrict__ t1,
                                              const __hip_bfloat16* __restrict__ U,
                                              __hip_bfloat16* __restrict__ kqv) {
    size_t i = (size_t)blockIdx.x * 256 + threadIdx.x; // 3*16*2048*64
    int s = (int)(i & 63);
    size_t rest = i >> 6;
    int t = (int)(rest & (T_SEQ - 1));
    int gh = (int)(rest >> 11);
    const short8* trow = (const short8*)(t1 + (size_t)t * NKQV + gh * RH);
    const short8* urow = (const short8*)(U + ((size_t)gh * HSZ + s) * RH);
    short8 ta = trow[0], tb = trow[1];
    short8 ua = urow[0], ub = urow[1];
    float acc = 0.f;
#pragma unroll
    for (int j = 0; j < 8; ++j) {
        acc += bfbits2f((ushort_t)ta[j]) * bfbits2f((ushort_t)ua[j]);
        acc += bfbits2f((ushort_t)tb[j]) * bfbits2f((ushort_t)ub[j]);
    }
    kqv[i] = __float2bfloat16(acc);
}

// --------------------------- V transpose per head --------------------------
__global__ __launch_bounds__(256) void vtrans_k(const __hip_bfloat16* __restrict__ vb,
                                                __hip_bfloat16* __restrict__ vt) {
    __shared__ short Ts[64][72];
    const int ti = blockIdx.x, h = blockIdx.y, tid = threadIdx.x;
    const int tl = tid >> 2, sc = (tid & 3) * 16;
    const short* src = (const short*)(vb + ((size_t)h * T_SEQ + ti * 64 + tl) * HSZ + sc);
    short8 a = ((const short8*)src)[0];
    short8 b = ((const short8*)src)[1];
#pragma unroll
    for (int j = 0; j < 8; ++j) { Ts[sc + j][tl] = a[j]; Ts[sc + 8 + j][tl] = b[j]; }
    __syncthreads();
    const int s = tid >> 2;
    short8 o0, o1;
#pragma unroll
    for (int j = 0; j < 8; ++j) { o0[j] = Ts[s][sc + j]; o1[j] = Ts[s][sc + 8 + j]; }
    short* dst = (short*)(vt + ((size_t)h * HSZ + s) * T_SEQ + ti * 64 + sc);
    ((short8*)dst)[0] = o0;
    ((short8*)dst)[1] = o1;
}

// ----------------- MFMA flash attention with causal key-split --------------
// Entry E in [0,320) per head: tile ti (16 q rows), split p over keys
// [p*512, min(t0+16, p*512+512)). a = ti>>5 = #extra splits; groups:
// a=0:[0,32) a=1:[32,96) a=2:[96,192) a=3:[192,320). 4 waves/block.
// a==0 writes normalized bf16 to attout; else writes f32 partial (o,m,l).
__global__ __launch_bounds__(256) void attn2_k(const __hip_bfloat16* __restrict__ qb,
                                               const __hip_bfloat16* __restrict__ kb,
                                               const __hip_bfloat16* __restrict__ vtb,
                                               __hip_bfloat16* __restrict__ attout,
                                               float* __restrict__ po,
                                               float* __restrict__ ml) {
    __shared__ short P_s[2][4][16 * 72];
    const int tid = threadIdx.x, w = tid >> 6, ln = tid & 63;
    const int lr = ln & 15, lg = ln >> 4;
    const int h = blockIdx.y;
    const int E = blockIdx.x * 4 + w;
    const int a = (E < 32) ? 0 : (E < 96) ? 1 : (E < 192) ? 2 : 3;
    const int off = (a == 0) ? 0 : (a == 1) ? 32 : (a == 2) ? 96 : 192;
    const int r0 = E - off;
    const int b = r0 / (a + 1), p = r0 - b * (a + 1);
    const int ti = a * 32 + b, t0 = ti * 16;
    const int ub = p * 512;
    const int ue = min(t0 + 16, ub + 512);

    const size_t hb = (size_t)h * T_SEQ;
    const size_t vtbase = (size_t)h * HSZ * T_SEQ;
    const float SCL = 0.18033688011112042f; // 0.125 * log2(e)

    short8 qf0 = *(const short8*)(qb + (hb + t0 + lr) * HSZ + lg * 8);
    short8 qf1 = *(const short8*)(qb + (hb + t0 + lr) * HSZ + 32 + lg * 8);

    f32x4 acc[4] = {};
    float mrun = -3e38f, lrun = 0.f;
    int pbuf = 0;

    short8 kf[4][2];
#pragma unroll
    for (int g = 0; g < 4; ++g) {
        kf[g][0] = *(const short8*)(kb + (hb + ub + g * 16 + lr) * HSZ + lg * 8);
        kf[g][1] = *(const short8*)(kb + (hb + ub + g * 16 + lr) * HSZ + 32 + lg * 8);
    }

    for (int u0 = ub; u0 < ue; u0 += 64) {
        f32x4 st[4];
#pragma unroll
        for (int g = 0; g < 4; ++g) {
            f32x4 z = {};
            z = __builtin_amdgcn_mfma_f32_16x16x32_bf16(kf[g][0], qf0, z, 0, 0, 0);
            st[g] = __builtin_amdgcn_mfma_f32_16x16x32_bf16(kf[g][1], qf1, z, 0, 0, 0);
        }

        const int un = u0 + 64;
        if (un < ue) {
#pragma unroll
            for (int g = 0; g < 4; ++g) {
                kf[g][0] = *(const short8*)(kb + (hb + un + g * 16 + lr) * HSZ + lg * 8);
                kf[g][1] = *(const short8*)(kb + (hb + un + g * 16 + lr) * HSZ + 32 + lg * 8);
            }
        }
        short8 vf[4][2];
#pragma unroll
        for (int dt = 0; dt < 4; ++dt) {
            vf[dt][0] = *(const short8*)(vtb + vtbase + (size_t)(dt * 16 + lr) * T_SEQ + u0 + lg * 8);
            vf[dt][1] = *(const short8*)(vtb + vtbase + (size_t)(dt * 16 + lr) * T_SEQ + u0 + 32 + lg * 8);
        }

        const int qg = t0 + lr;
        float sv[16];
#pragma unroll
        for (int g = 0; g < 4; ++g) {
            const bool needm = (u0 + g * 16 + 15 > t0);
#pragma unroll
            for (int r = 0; r < 4; ++r) {
                float v = st[g][r] * SCL;
                if (needm && (u0 + g * 16 + lg * 4 + r > qg)) v = -1e30f;
                sv[g * 4 + r] = v;
            }
        }
        float tm = sv[0];
#pragma unroll
        for (int j = 1; j < 16; ++j) tm = fmaxf(tm, sv[j]);
        tm = fmaxf(tm, __shfl_xor(tm, 16));
        tm = fmaxf(tm, __shfl_xor(tm, 32));
        const float mnew = fmaxf(mrun, tm);
        const float corr = exp2f(mrun - mnew);
        float pv[16];
        float ls = 0.f;
#pragma unroll
        for (int j = 0; j < 16; ++j) { pv[j] = exp2f(sv[j] - mnew); ls += pv[j]; }
        ls += __shfl_xor(ls, 16);
        ls += __shfl_xor(ls, 32);
        lrun = lrun * corr + ls;
#pragma unroll
        for (int dt = 0; dt < 4; ++dt) acc[dt] *= corr;

        uint_t* pw = (uint_t*)P_s[pbuf][w];
        const int wb = lr * 36 + lg * 2;
#pragma unroll
        for (int g = 0; g < 4; ++g) {
            pw[wb + g * 8 + 0] = pack2bf(pv[g * 4 + 0], pv[g * 4 + 1]);
            pw[wb + g * 8 + 1] = pack2bf(pv[g * 4 + 2], pv[g * 4 + 3]);
        }
        asm volatile("s_waitcnt lgkmcnt(0)" ::: "memory");
        short8 pf0 = *(const short8*)(&P_s[pbuf][w][lr * 72 + lg * 8]);
        short8 pf1 = *(const short8*)(&P_s[pbuf][w][lr * 72 + 32 + lg * 8]);

#pragma unroll
        for (int dt = 0; dt < 4; ++dt) {
            acc[dt] = __builtin_amdgcn_mfma_f32_16x16x32_bf16(vf[dt][0], pf0, acc[dt], 0, 0, 0);
            acc[dt] = __builtin_amdgcn_mfma_f32_16x16x32_bf16(vf[dt][1], pf1, acc[dt], 0, 0, 0);
        }

        mrun = mnew;
        pbuf ^= 1;
    }

    if (a == 0) {
        // single split: normalize and write bf16
        const float inv = 1.f / lrun;
#pragma unroll
        for (int dt = 0; dt < 4; ++dt) {
#pragma unroll
            for (int r = 0; r < 4; r += 2) {
                uint_t pk = pack2bf(acc[dt][r] * inv, acc[dt][r + 1] * inv);
                *(uint_t*)(attout + (size_t)(t0 + lr) * DMODEL + h * HSZ + dt * 16 + lg * 4 + r) = pk;
            }
        }
    } else {
        // partial: unnormalized o (f32) + (m, l) per q row
        const size_t eb = ((size_t)h * 128 + ti) * 4 + p;
        float* pob = po + eb * (16 * 64);
#pragma unroll
        for (int dt = 0; dt < 4; ++dt)
            *(f32x4*)&pob[lr * 64 + dt * 16 + lg * 4] = acc[dt];
        if (lg == 0) {
            ml[eb * 32 + lr * 2 + 0] = mrun;
            ml[eb * 32 + lr * 2 + 1] = lrun;
        }
    }
}

// -------------------- combine key-split partials (ti >= 32) ----------------
__global__ __launch_bounds__(256) void comb_k(const float* __restrict__ po,
                                              const float* __restrict__ ml,
                                              __hip_bfloat16* __restrict__ attout) {
    const int ti = 32 + blockIdx.x;
    const int h = blockIdx.y;
    const int ns = (ti >> 5) + 1;                 // 2..4
    const int tid = threadIdx.x;
    const int q = tid >> 4, c = (tid & 15) * 4;
    const size_t eb0 = ((size_t)h * 128 + ti) * 4;

    float mv[4], lv[4];
    float m = -3e38f;
    for (int p = 0; p < ns; ++p) {
        mv[p] = ml[(eb0 + p) * 32 + q * 2 + 0];
        lv[p] = ml[(eb0 + p) * 32 + q * 2 + 1];
        m = fmaxf(m, mv[p]);
    }
    float l = 0.f;
    float4 o = {0.f, 0.f, 0.f, 0.f};
    for (int p = 0; p < ns; ++p) {
        const float wgt = exp2f(mv[p] - m);
        l += lv[p] * wgt;
        float4 v = *(const float4*)&po[(eb0 + p) * (16 * 64) + q * 64 + c];
        o.x += v.x * wgt; o.y += v.y * wgt; o.z += v.z * wgt; o.w += v.w * wgt;
    }
    const float inv = 1.f / l;
    uint2 pk;
    pk.x = pack2bf(o.x * inv, o.y * inv);
    pk.y = pack2bf(o.z * inv, o.w * inv);
    *(uint2*)(attout + (size_t)(ti * 16 + q) * DMODEL + h * HSZ + c) = pk;
}

// ---------------------------------------------------------------------------
extern "C" void kernel_launch(void* const* d_in, const int* in_sizes, int n_in,
                              void* d_out, int out_size, void* d_ws, size_t ws_size,
                              hipStream_t stream) {
    const int* idx = (const int*)d_in[0];
    const float* tok_emb = (const float*)d_in[1];
    const float* pos_emb = (const float*)d_in[2];
    const float* ln1_w = (const float*)d_in[3];
    const float* ln1_b = (const float*)d_in[4];
    const float* ln2_w = (const float*)d_in[5];
    const float* ln2_b = (const float*)d_in[6];
    const float* kqv_V = (const float*)d_in[7];
    const float* kqv_z = (const float*)d_in[8];
    const float* kqv_U = (const float*)d_in[9];
    const float* proj_V = (const float*)d_in[10];
    const float* proj_z = (const float*)d_in[11];
    const float* proj_U = (const float*)d_in[12];
    const float* f1_V = (const float*)d_in[13];
    const float* f1_z = (const float*)d_in[14];
    const float* f1_U = (const float*)d_in[15];
    const float* f2_V = (const float*)d_in[16];
    const float* f2_z = (const float*)d_in[17];
    const float* f2_U = (const float*)d_in[18];
    const float* lnf_w = (const float*)d_in[19];
    const float* lnf_b = (const float*)d_in[20];
    const float* lm_w = (const float*)d_in[21];

    // ---------------- workspace layout ----------------
    char* W = (char*)d_ws;
    float* x = (float*)W;                 W += (size_t)T_SEQ * DMODEL * 4;
    __hip_bfloat16* hbuf = (__hip_bfloat16*)W; W += (size_t)T_SEQ * DMODEL * 2;
    __hip_bfloat16* t1 = (__hip_bfloat16*)W;   W += (size_t)T_SEQ * NKQV * 2;
    __hip_bfloat16* kqvb = (__hip_bfloat16*)W; W += (size_t)3 * NHEAD * T_SEQ * HSZ * 2;
    __hip_bfloat16* vtb = (__hip_bfloat16*)W;  W += (size_t)NHEAD * HSZ * T_SEQ * 2;
    __hip_bfloat16* attb = (__hip_bfloat16*)W; W += (size_t)T_SEQ * DMODEL * 2;
    // ffb (16.8 MB) time-overlaid with attention partials po (33.5 MB):
    // attn writes po+ml -> comb reads -> ffn overwrites region. Disjoint lifetimes.
    __hip_bfloat16* ffb = (__hip_bfloat16*)W;  // T_SEQ*FFDIM*2 = 16.8 MB
    float* po = (float*)W;                W += (size_t)NHEAD * 128 * 4 * 16 * 64 * 4; // 33.6 MB
    float* ml = (float*)W;                W += (size_t)NHEAD * 128 * 4 * 32 * 4;      // 1.05 MB
    __hip_bfloat16* wkV = (__hip_bfloat16*)W;  W += (size_t)NLAYER * NKQV * DMODEL * 2;
    __hip_bfloat16* wkU = (__hip_bfloat16*)W;  W += (size_t)NLAYER * 3 * NHEAD * HSZ * RH * 2;
    __hip_bfloat16* wpV = (__hip_bfloat16*)W;  W += (size_t)NLAYER * RP * DMODEL * 2;
    __hip_bfloat16* wpU = (__hip_bfloat16*)W;  W += (size_t)NLAYER * DMODEL * RP * 2;
    __hip_bfloat16* w1V = (__hip_bfloat16*)W;  W += (size_t)NLAYER * RF * DMODEL * 2;
    __hip_bfloat16* w1U = (__hip_bfloat16*)W;  W += (size_t)NLAYER * FFDIM * RF * 2;
    __hip_bfloat16* w2V = (__hip_bfloat16*)W;  W += (size_t)NLAYER * RF * FFDIM * 2;
    __hip_bfloat16* w2U = (__hip_bfloat16*)W;  W += (size_t)NLAYER * DMODEL * RF * 2;
    __hip_bfloat16* wlm = (__hip_bfloat16*)W;  W += (size_t)VOCAB * DMODEL * 2;

    auto cvt = [&](const float* src, __hip_bfloat16* dst, size_t n) {
        int n4 = (int)(n / 4);
        cvt_k<<<dim3((n4 + 255) / 256), dim3(256), 0, stream>>>(src, dst, n4);
    };
    cvt(kqv_V, wkV, (size_t)NLAYER * NKQV * DMODEL);
    cvt(kqv_U, wkU, (size_t)NLAYER * 3 * NHEAD * HSZ * RH);
    cvt(proj_V, wpV, (size_t)NLAYER * RP * DMODEL);
    cvt(proj_U, wpU, (size_t)NLAYER * DMODEL * RP);
    cvt(f1_V, w1V, (size_t)NLAYER * RF * DMODEL);
    cvt(f1_U, w1U, (size_t)NLAYER * FFDIM * RF);
    cvt(f2_V, w2V, (size_t)NLAYER * RF * FFDIM);
    cvt(f2_U, w2U, (size_t)NLAYER * DMODEL * RF);
    cvt(lm_w, wlm, (size_t)VOCAB * DMODEL);

    embed_k<<<dim3(T_SEQ * DMODEL / 4 / 256), dim3(256), 0, stream>>>(idx, tok_emb, pos_emb, x);

    const int M = T_SEQ;
    for (int l = 0; l < NLAYER; ++l) {
        ln_k<<<dim3(T_SEQ), dim3(256), 0, stream>>>(x, ln1_w + l * DMODEL, ln1_b + l * DMODEL, hbuf);
        gemm_t<64, 64, 0><<<dim3((M / 64) * (NKQV / 64)), dim3(256), 0, stream>>>(
            hbuf, wkV + (size_t)l * NKQV * DMODEL, kqv_z + (size_t)l * NKQV,
            t1, nullptr, M, NKQV, DMODEL);
        kqv2_k<<<dim3(3 * NHEAD * T_SEQ * HSZ / 256), dim3(256), 0, stream>>>(
            t1, wkU + (size_t)l * 3 * NHEAD * HSZ * RH, kqvb);
        {
            const __hip_bfloat16* kk = kqvb;
            const __hip_bfloat16* qq = kqvb + (size_t)NHEAD * T_SEQ * HSZ;
            const __hip_bfloat16* vv = kqvb + (size_t)2 * NHEAD * T_SEQ * HSZ;
            vtrans_k<<<dim3(T_SEQ / 64, NHEAD), dim3(256), 0, stream>>>(vv, vtb);
            attn2_k<<<dim3(80, NHEAD), dim3(256), 0, stream>>>(qq, kk, vtb, attb, po, ml);
            comb_k<<<dim3(96, NHEAD), dim3(256), 0, stream>>>(po, ml, attb);
        }
        gemm_t<64, 64, 0><<<dim3((M / 64) * (RP / 64)), dim3(256), 0, stream>>>(
            attb, wpV + (size_t)l * RP * DMODEL, proj_z + (size_t)l * RP,
            t1, nullptr, M, RP, DMODEL);
        gemm_t<128, 128, 2><<<dim3((M / 128) * (DMODEL / 128)), dim3(256), 0, stream>>>(
            t1, wpU + (size_t)l * DMODEL * RP, nullptr,
            nullptr, x, M, DMODEL, RP);
        ln_k<<<dim3(T_SEQ), dim3(256), 0, stream>>>(x, ln2_w + l * DMODEL, ln2_b + l * DMODEL, hbuf);
        gemm_t<64, 64, 0><<<dim3((M / 64) * (RF / 64)), dim3(256), 0, stream>>>(
            hbuf, w1V + (size_t)l * RF * DMODEL, f1_z + (size_t)l * RF,
            t1, nullptr, M, RF, DMODEL);
        gemm_t<128, 128, 1><<<dim3((M / 128) * (FFDIM / 128)), dim3(256), 0, stream>>>(
            t1, w1U + (size_t)l * FFDIM * RF, nullptr,
            ffb, nullptr, M, FFDIM, RF);
        gemm_t<64, 64, 0><<<dim3((M / 64) * (RF / 64)), dim3(256), 0, stream>>>(
            ffb, w2V + (size_t)l * RF * FFDIM, f2_z + (size_t)l * RF,
            t1, nullptr, M, RF, FFDIM);
        gemm_t<128, 128, 2><<<dim3((M / 128) * (DMODEL / 128)), dim3(256), 0, stream>>>(
            t1, w2U + (size_t)l * DMODEL * RF, nullptr,
            nullptr, x, M, DMODEL, RF);
    }
    ln_k<<<dim3(T_SEQ), dim3(256), 0, stream>>>(x, lnf_w, lnf_b, hbuf);
    gemm_t<128, 128, 3><<<dim3((M / 128) * (VOCAB / 128)), dim3(256), 0, stream>>>(
        hbuf, wlm, nullptr, nullptr, (float*)d_out, M, VOCAB, DMODEL);
}

// Round 10
// 1318.155 us; speedup vs baseline: 1.0570x; 1.0313x over previous
//
#include <hip/hip_runtime.h>
#include <hip/hip_bf16.h>

// ---------------------------------------------------------------------------
// TransformerSquared forward on MI355X.
// R9: exact restore of the Round-4 passing configuration (1336us) —
// gemm_t (m97-structure, XOR swizzle) for all GEMMs incl. logits;
// attn_k KVBLK=64. ONLY change: attn_k block-index remap (bijective)
// clustering each XCD onto 2 heads for K/Vt L2 residency.
// ---------------------------------------------------------------------------

#define T_SEQ 2048
#define DMODEL 1024
#define NHEAD 16
#define HSZ 64
#define NLAYER 4
#define FFDIM 4096
#define RH 16
#define RP 256
#define RF 256
#define VOCAB 32000
#define NKQV (3 * NHEAD * RH) // 768

typedef short short8 __attribute__((ext_vector_type(8)));
typedef float f32x4 __attribute__((ext_vector_type(4)));
typedef unsigned int uint_t;
typedef unsigned short ushort_t;

__device__ __forceinline__ float bfbits2f(uint_t bits16_in_low) {
    uint_t b = bits16_in_low << 16;
    float f;
    __builtin_memcpy(&f, &b, 4);
    return f;
}
__device__ __forceinline__ ushort_t f2bfu(float f) {
    union { __hip_bfloat16 b; ushort_t u; } cv;
    cv.b = __float2bfloat16(f);
    return cv.u;
}
__device__ __forceinline__ uint_t pack2bf(float a, float b) {
    return (uint_t)f2bfu(a) | ((uint_t)f2bfu(b) << 16);
}

// async global->LDS, 16 bytes per lane. LDS dest = wave-uniform base + lane*16.
__device__ __forceinline__ void gld16(const __hip_bfloat16* g, short* l) {
    __builtin_amdgcn_global_load_lds(
        (const __attribute__((address_space(1))) void*)g,
        (__attribute__((address_space(3))) void*)l, 16, 0, 0);
}

// ------------------------------- f32 -> bf16 -------------------------------
__global__ __launch_bounds__(256) void cvt_k(const float* __restrict__ in,
                                             __hip_bfloat16* __restrict__ out, int n4) {
    int i = blockIdx.x * 256 + threadIdx.x;
    if (i >= n4) return;
    float4 v = ((const float4*)in)[i];
    ushort4 o;
    o.x = f2bfu(v.x); o.y = f2bfu(v.y); o.z = f2bfu(v.z); o.w = f2bfu(v.w);
    ((ushort4*)out)[i] = o;
}

// ------------------------------- embedding ---------------------------------
__global__ __launch_bounds__(256) void embed_k(const int* __restrict__ idx,
                                               const float* __restrict__ tok,
                                               const float* __restrict__ pos,
                                               float* __restrict__ x) {
    int i = blockIdx.x * 256 + threadIdx.x;          // over T*D/4
    int d4 = i & (DMODEL / 4 - 1);
    int t = i >> 8;                                   // D/4 = 256
    int tk = idx[t];
    float4 a = ((const float4*)(tok + (size_t)tk * DMODEL))[d4];
    float4 p = ((const float4*)(pos + (size_t)t * DMODEL))[d4];
    a.x += p.x; a.y += p.y; a.z += p.z; a.w += p.w;
    ((float4*)(x + (size_t)t * DMODEL))[d4] = a;
}

// ------------------------------- layernorm ---------------------------------
__global__ __launch_bounds__(256) void ln_k(const float* __restrict__ xin,
                                            const float* __restrict__ w,
                                            const float* __restrict__ b,
                                            __hip_bfloat16* __restrict__ out) {
    const int row = blockIdx.x, tid = threadIdx.x;
    const float4 v = ((const float4*)(xin + (size_t)row * DMODEL))[tid];
    float s = v.x + v.y + v.z + v.w;
    float q = v.x * v.x + v.y * v.y + v.z * v.z + v.w * v.w;
    for (int off = 32; off; off >>= 1) { s += __shfl_xor(s, off); q += __shfl_xor(q, off); }
    __shared__ float rs_[4], rq_[4];
    if ((tid & 63) == 0) { rs_[tid >> 6] = s; rq_[tid >> 6] = q; }
    __syncthreads();
    s = rs_[0] + rs_[1] + rs_[2] + rs_[3];
    q = rq_[0] + rq_[1] + rq_[2] + rq_[3];
    const float mean = s * (1.f / DMODEL);
    const float var = q * (1.f / DMODEL) - mean * mean;
    const float rstd = rsqrtf(var + 1e-5f);
    const float4 wv = ((const float4*)w)[tid];
    const float4 bv = ((const float4*)b)[tid];
    ushort4 o;
    o.x = f2bfu((v.x - mean) * rstd * wv.x + bv.x);
    o.y = f2bfu((v.y - mean) * rstd * wv.y + bv.y);
    o.z = f2bfu((v.z - mean) * rstd * wv.z + bv.z);
    o.w = f2bfu((v.w - mean) * rstd * wv.w + bv.w);
    ((ushort4*)out)[(size_t)row * (DMODEL / 4) + tid] = o;
}

// --------------------------- generic GEMM (A * B^T) ------------------------
// m97-structure, 2-barrier, both-sides XOR swizzle (verified 0 conflicts R4).
template <int BM, int BN, int MODE>
__global__ __launch_bounds__(256) void gemm_t(const __hip_bfloat16* __restrict__ A,
                                              const __hip_bfloat16* __restrict__ B,
                                              const float* __restrict__ colscale,
                                              __hip_bfloat16* __restrict__ Cb,
                                              float* __restrict__ Cf,
                                              int M, int N, int K) {
    constexpr int WM = (BN >= 128) ? 2 : 4;
    constexpr int WN = 4 / WM;
    constexpr int TM = BM / WM / 16;
    constexpr int TN = BN / WN / 16;
    constexpr int IA = BM / 32;     // gld16 iters for A tile
    constexpr int IB = BN / 32;
    __shared__ short As[BM * 64];
    __shared__ short Bs[BN * 64];
    const int tid = threadIdx.x;
    const int w = tid >> 6, ln = tid & 63, lr = ln & 15, lg = ln >> 4;
    const int GM = M / BM;

    const int nwg = gridDim.x;
    const int cpx = nwg >> 3;
    const int wg = (blockIdx.x & 7) * cpx + (blockIdx.x >> 3);
    const int bm = wg % GM, bn = wg / GM;
    const int wm = w / WN, wn = w % WN;

    f32x4 acc[TM][TN] = {};

    const int srow = tid >> 3;
    const int scol = (((tid & 7) ^ ((tid >> 3) & 7)) * 8);
    const __hip_bfloat16* Ag = A + (size_t)(bm * BM + srow) * K + scol;
    const __hip_bfloat16* Bg = B + (size_t)(bn * BN + srow) * K + scol;

    for (int kt = 0; kt < K; kt += 64) {
        __syncthreads();   // previous tile consumed
#pragma unroll
        for (int i = 0; i < IA; ++i)
            gld16(Ag + (size_t)(i * 32) * K + kt, &As[i * 2048 + w * 512]);
#pragma unroll
        for (int i = 0; i < IB; ++i)
            gld16(Bg + (size_t)(i * 32) * K + kt, &Bs[i * 2048 + w * 512]);
        __syncthreads();   // drains vmcnt + barrier

#pragma unroll
        for (int kk = 0; kk < 2; ++kk) {
            short8 af[TM], bf[TN];
#pragma unroll
            for (int m = 0; m < TM; ++m) {
                const int row = wm * (BM / WM) + m * 16 + lr;
                af[m] = *(const short8*)&As[row * 64 + (((kk * 4 + lg) ^ (lr & 7)) * 8)];
            }
#pragma unroll
            for (int n = 0; n < TN; ++n) {
                const int row = wn * (BN / WN) + n * 16 + lr;
                bf[n] = *(const short8*)&Bs[row * 64 + (((kk * 4 + lg) ^ (lr & 7)) * 8)];
            }
#pragma unroll
            for (int m = 0; m < TM; ++m)
#pragma unroll
                for (int n = 0; n < TN; ++n)
                    acc[m][n] = __builtin_amdgcn_mfma_f32_16x16x32_bf16(af[m], bf[n], acc[m][n], 0, 0, 0);
        }
    }

#pragma unroll
    for (int n = 0; n < TN; ++n) {
        const int col = bn * BN + wn * (BN / WN) + n * 16 + lr;
        float cs = 1.0f;
        if (MODE == 0 && colscale) cs = colscale[col];
#pragma unroll
        for (int m = 0; m < TM; ++m) {
#pragma unroll
            for (int rr = 0; rr < 4; ++rr) {
                const int row = bm * BM + wm * (BM / WM) + m * 16 + lg * 4 + rr;
                float v = acc[m][n][rr];
                const size_t o = (size_t)row * N + col;
                if (MODE == 0) {
                    Cb[o] = __float2bfloat16(v * cs);
                } else if (MODE == 1) {
                    v = 0.5f * v * (1.0f + erff(v * 0.70710678118654752f));
                    Cb[o] = __float2bfloat16(v);
                } else if (MODE == 2) {
                    Cf[o] += v;
                } else {
                    Cf[o] = v;
                }
            }
        }
    }
}

// ----------------------- per-head SVF U-projection (K=16) ------------------
__global__ __launch_bounds__(256) void kqv2_k(const __hip_bfloat16* __restrict__ t1,
                                              const __hip_bfloat16* __restrict__ U,
                                              __hip_bfloat16* __restrict__ kqv) {
    size_t i = (size_t)blockIdx.x * 256 + threadIdx.x; // 3*16*2048*64
    int s = (int)(i & 63);
    size_t rest = i >> 6;
    int t = (int)(rest & (T_SEQ - 1));
    int gh = (int)(rest >> 11);
    const short8* trow = (const short8*)(t1 + (size_t)t * NKQV + gh * RH);
    const short8* urow = (const short8*)(U + ((size_t)gh * HSZ + s) * RH);
    short8 ta = trow[0], tb = trow[1];
    short8 ua = urow[0], ub = urow[1];
    float acc = 0.f;
#pragma unroll
    for (int j = 0; j < 8; ++j) {
        acc += bfbits2f((ushort_t)ta[j]) * bfbits2f((ushort_t)ua[j]);
        acc += bfbits2f((ushort_t)tb[j]) * bfbits2f((ushort_t)ub[j]);
    }
    kqv[i] = __float2bfloat16(acc);
}

// --------------------------- V transpose per head --------------------------
__global__ __launch_bounds__(256) void vtrans_k(const __hip_bfloat16* __restrict__ vb,
                                                __hip_bfloat16* __restrict__ vt) {
    __shared__ short Ts[64][72];
    const int ti = blockIdx.x, h = blockIdx.y, tid = threadIdx.x;
    const int tl = tid >> 2, sc = (tid & 3) * 16;
    const short* src = (const short*)(vb + ((size_t)h * T_SEQ + ti * 64 + tl) * HSZ + sc);
    short8 a = ((const short8*)src)[0];
    short8 b = ((const short8*)src)[1];
#pragma unroll
    for (int j = 0; j < 8; ++j) { Ts[sc + j][tl] = a[j]; Ts[sc + 8 + j][tl] = b[j]; }
    __syncthreads();
    const int s = tid >> 2;
    short8 o0, o1;
#pragma unroll
    for (int j = 0; j < 8; ++j) { o0[j] = Ts[s][sc + j]; o1[j] = Ts[s][sc + 8 + j]; }
    short* dst = (short*)(vt + ((size_t)h * HSZ + s) * T_SEQ + ti * 64 + sc);
    ((short8*)dst)[0] = o0;
    ((short8*)dst)[1] = o1;
}

// --------------------------- MFMA flash attention --------------------------
// 1 wave = 16 q rows, KVBLK = 64 keys/iter (4 indep QK chains, 8 PV mfma).
// Block = 4 waves, strided q tiles: t0 = bi*16 + w*512.
// R9: bijective block-remap so each XCD serves only 2 heads (K/Vt L2-resident):
//   f = y*32 + x; h = (f&7)*2 + ((f>>3)&1); bi = f>>4.
__global__ __launch_bounds__(256) void attn_k(const __hip_bfloat16* __restrict__ qb,
                                              const __hip_bfloat16* __restrict__ kb,
                                              const __hip_bfloat16* __restrict__ vtb,
                                              __hip_bfloat16* __restrict__ attout) {
    __shared__ short P_s[2][4][16 * 72];  // [dbuf][wave][16 q x 64 u], stride 72
    const int tid = threadIdx.x, w = tid >> 6, ln = tid & 63;
    const int lr = ln & 15, lg = ln >> 4;
    const int f = blockIdx.y * 32 + blockIdx.x;
    const int h = ((f & 7) << 1) | ((f >> 3) & 1);
    const int bi = f >> 4;
    const int t0 = bi * 16 + w * 512;
    const size_t hb = (size_t)h * T_SEQ;
    const size_t vtbase = (size_t)h * HSZ * T_SEQ;

    short8 qf0 = *(const short8*)(qb + (hb + t0 + lr) * HSZ + lg * 8);
    short8 qf1 = *(const short8*)(qb + (hb + t0 + lr) * HSZ + 32 + lg * 8);

    f32x4 acc[4] = {};
    float mrun = -3e38f, lrun = 0.f;
    int pbuf = 0;

    short8 kf[4][2];
#pragma unroll
    for (int g = 0; g < 4; ++g) {
        kf[g][0] = *(const short8*)(kb + (hb + g * 16 + lr) * HSZ + lg * 8);
        kf[g][1] = *(const short8*)(kb + (hb + g * 16 + lr) * HSZ + 32 + lg * 8);
    }

    for (int u0 = 0; u0 <= t0 + 15; u0 += 64) {
        f32x4 st[4];
#pragma unroll
        for (int g = 0; g < 4; ++g) {
            f32x4 z = {};
            z = __builtin_amdgcn_mfma_f32_16x16x32_bf16(kf[g][0], qf0, z, 0, 0, 0);
            st[g] = __builtin_amdgcn_mfma_f32_16x16x32_bf16(kf[g][1], qf1, z, 0, 0, 0);
        }

        const int un = u0 + 64;
        if (un <= t0 + 15) {
#pragma unroll
            for (int g = 0; g < 4; ++g) {
                kf[g][0] = *(const short8*)(kb + (hb + un + g * 16 + lr) * HSZ + lg * 8);
                kf[g][1] = *(const short8*)(kb + (hb + un + g * 16 + lr) * HSZ + 32 + lg * 8);
            }
        }
        short8 vf[4][2];
#pragma unroll
        for (int dt = 0; dt < 4; ++dt) {
            vf[dt][0] = *(const short8*)(vtb + vtbase + (size_t)(dt * 16 + lr) * T_SEQ + u0 + lg * 8);
            vf[dt][1] = *(const short8*)(vtb + vtbase + (size_t)(dt * 16 + lr) * T_SEQ + u0 + 32 + lg * 8);
        }

        const int qg = t0 + lr;
        float sv[16];
#pragma unroll
        for (int g = 0; g < 4; ++g) {
            const bool needm = (u0 + g * 16 + 15 > t0);
#pragma unroll
            for (int r = 0; r < 4; ++r) {
                float v = st[g][r] * 0.125f;
                if (needm && (u0 + g * 16 + lg * 4 + r > qg)) v = -1e30f;
                sv[g * 4 + r] = v;
            }
        }
        float tm = sv[0];
#pragma unroll
        for (int j = 1; j < 16; ++j) tm = fmaxf(tm, sv[j]);
        tm = fmaxf(tm, __shfl_xor(tm, 16));
        tm = fmaxf(tm, __shfl_xor(tm, 32));
        const float mnew = fmaxf(mrun, tm);
        const float corr = __expf(mrun - mnew);
        float pv[16];
        float ls = 0.f;
#pragma unroll
        for (int j = 0; j < 16; ++j) { pv[j] = __expf(sv[j] - mnew); ls += pv[j]; }
        ls += __shfl_xor(ls, 16);
        ls += __shfl_xor(ls, 32);
        lrun = lrun * corr + ls;
#pragma unroll
        for (int dt = 0; dt < 4; ++dt) acc[dt] *= corr;

        uint_t* pw = (uint_t*)P_s[pbuf][w];
        const int wb = lr * 36 + lg * 2;
#pragma unroll
        for (int g = 0; g < 4; ++g) {
            pw[wb + g * 8 + 0] = pack2bf(pv[g * 4 + 0], pv[g * 4 + 1]);
            pw[wb + g * 8 + 1] = pack2bf(pv[g * 4 + 2], pv[g * 4 + 3]);
        }
        asm volatile("s_waitcnt lgkmcnt(0)" ::: "memory");
        short8 pf0 = *(const short8*)(&P_s[pbuf][w][lr * 72 + lg * 8]);
        short8 pf1 = *(const short8*)(&P_s[pbuf][w][lr * 72 + 32 + lg * 8]);

#pragma unroll
        for (int dt = 0; dt < 4; ++dt) {
            acc[dt] = __builtin_amdgcn_mfma_f32_16x16x32_bf16(vf[dt][0], pf0, acc[dt], 0, 0, 0);
            acc[dt] = __builtin_amdgcn_mfma_f32_16x16x32_bf16(vf[dt][1], pf1, acc[dt], 0, 0, 0);
        }

        mrun = mnew;
        pbuf ^= 1;
    }

    const float inv = 1.f / lrun;
#pragma unroll
    for (int dt = 0; dt < 4; ++dt) {
#pragma unroll
        for (int r = 0; r < 4; r += 2) {
            uint_t pk = pack2bf(acc[dt][r] * inv, acc[dt][r + 1] * inv);
            *(uint_t*)(attout + (size_t)(t0 + lr) * DMODEL + h * HSZ + dt * 16 + lg * 4 + r) = pk;
        }
    }
}

// ---------------------------------------------------------------------------
extern "C" void kernel_launch(void* const* d_in, const int* in_sizes, int n_in,
                              void* d_out, int out_size, void* d_ws, size_t ws_size,
                              hipStream_t stream) {
    const int* idx = (const int*)d_in[0];
    const float* tok_emb = (const float*)d_in[1];
    const float* pos_emb = (const float*)d_in[2];
    const float* ln1_w = (const float*)d_in[3];
    const float* ln1_b = (const float*)d_in[4];
    const float* ln2_w = (const float*)d_in[5];
    const float* ln2_b = (const float*)d_in[6];
    const float* kqv_V = (const float*)d_in[7];
    const float* kqv_z = (const float*)d_in[8];
    const float* kqv_U = (const float*)d_in[9];
    const float* proj_V = (const float*)d_in[10];
    const float* proj_z = (const float*)d_in[11];
    const float* proj_U = (const float*)d_in[12];
    const float* f1_V = (const float*)d_in[13];
    const float* f1_z = (const float*)d_in[14];
    const float* f1_U = (const float*)d_in[15];
    const float* f2_V = (const float*)d_in[16];
    const float* f2_z = (const float*)d_in[17];
    const float* f2_U = (const float*)d_in[18];
    const float* lnf_w = (const float*)d_in[19];
    const float* lnf_b = (const float*)d_in[20];
    const float* lm_w = (const float*)d_in[21];

    // ---------------- workspace layout ----------------
    char* W = (char*)d_ws;
    float* x = (float*)W;                 W += (size_t)T_SEQ * DMODEL * 4;
    __hip_bfloat16* hbuf = (__hip_bfloat16*)W; W += (size_t)T_SEQ * DMODEL * 2;
    __hip_bfloat16* t1 = (__hip_bfloat16*)W;   W += (size_t)T_SEQ * NKQV * 2;
    __hip_bfloat16* kqvb = (__hip_bfloat16*)W; W += (size_t)3 * NHEAD * T_SEQ * HSZ * 2;
    __hip_bfloat16* vtb = (__hip_bfloat16*)W;  W += (size_t)NHEAD * HSZ * T_SEQ * 2;
    __hip_bfloat16* attb = (__hip_bfloat16*)W; W += (size_t)T_SEQ * DMODEL * 2;
    __hip_bfloat16* ffb = (__hip_bfloat16*)W;  W += (size_t)T_SEQ * FFDIM * 2;
    __hip_bfloat16* wkV = (__hip_bfloat16*)W;  W += (size_t)NLAYER * NKQV * DMODEL * 2;
    __hip_bfloat16* wkU = (__hip_bfloat16*)W;  W += (size_t)NLAYER * 3 * NHEAD * HSZ * RH * 2;
    __hip_bfloat16* wpV = (__hip_bfloat16*)W;  W += (size_t)NLAYER * RP * DMODEL * 2;
    __hip_bfloat16* wpU = (__hip_bfloat16*)W;  W += (size_t)NLAYER * DMODEL * RP * 2;
    __hip_bfloat16* w1V = (__hip_bfloat16*)W;  W += (size_t)NLAYER * RF * DMODEL * 2;
    __hip_bfloat16* w1U = (__hip_bfloat16*)W;  W += (size_t)NLAYER * FFDIM * RF * 2;
    __hip_bfloat16* w2V = (__hip_bfloat16*)W;  W += (size_t)NLAYER * RF * FFDIM * 2;
    __hip_bfloat16* w2U = (__hip_bfloat16*)W;  W += (size_t)NLAYER * DMODEL * RF * 2;
    __hip_bfloat16* wlm = (__hip_bfloat16*)W;  W += (size_t)VOCAB * DMODEL * 2;

    auto cvt = [&](const float* src, __hip_bfloat16* dst, size_t n) {
        int n4 = (int)(n / 4);
        cvt_k<<<dim3((n4 + 255) / 256), dim3(256), 0, stream>>>(src, dst, n4);
    };
    cvt(kqv_V, wkV, (size_t)NLAYER * NKQV * DMODEL);
    cvt(kqv_U, wkU, (size_t)NLAYER * 3 * NHEAD * HSZ * RH);
    cvt(proj_V, wpV, (size_t)NLAYER * RP * DMODEL);
    cvt(proj_U, wpU, (size_t)NLAYER * DMODEL * RP);
    cvt(f1_V, w1V, (size_t)NLAYER * RF * DMODEL);
    cvt(f1_U, w1U, (size_t)NLAYER * FFDIM * RF);
    cvt(f2_V, w2V, (size_t)NLAYER * RF * FFDIM);
    cvt(f2_U, w2U, (size_t)NLAYER * DMODEL * RF);
    cvt(lm_w, wlm, (size_t)VOCAB * DMODEL);

    embed_k<<<dim3(T_SEQ * DMODEL / 4 / 256), dim3(256), 0, stream>>>(idx, tok_emb, pos_emb, x);

    const int M = T_SEQ;
    for (int l = 0; l < NLAYER; ++l) {
        ln_k<<<dim3(T_SEQ), dim3(256), 0, stream>>>(x, ln1_w + l * DMODEL, ln1_b + l * DMODEL, hbuf);
        gemm_t<64, 64, 0><<<dim3((M / 64) * (NKQV / 64)), dim3(256), 0, stream>>>(
            hbuf, wkV + (size_t)l * NKQV * DMODEL, kqv_z + (size_t)l * NKQV,
            t1, nullptr, M, NKQV, DMODEL);
        kqv2_k<<<dim3(3 * NHEAD * T_SEQ * HSZ / 256), dim3(256), 0, stream>>>(
            t1, wkU + (size_t)l * 3 * NHEAD * HSZ * RH, kqvb);
        {
            const __hip_bfloat16* kk = kqvb;
            const __hip_bfloat16* qq = kqvb + (size_t)NHEAD * T_SEQ * HSZ;
            const __hip_bfloat16* vv = kqvb + (size_t)2 * NHEAD * T_SEQ * HSZ;
            vtrans_k<<<dim3(T_SEQ / 64, NHEAD), dim3(256), 0, stream>>>(vv, vtb);
            attn_k<<<dim3(T_SEQ / 64, NHEAD), dim3(256), 0, stream>>>(qq, kk, vtb, attb);
        }
        gemm_t<64, 64, 0><<<dim3((M / 64) * (RP / 64)), dim3(256), 0, stream>>>(
            attb, wpV + (size_t)l * RP * DMODEL, proj_z + (size_t)l * RP,
            t1, nullptr, M, RP, DMODEL);
        gemm_t<128, 128, 2><<<dim3((M / 128) * (DMODEL / 128)), dim3(256), 0, stream>>>(
            t1, wpU + (size_t)l * DMODEL * RP, nullptr,
            nullptr, x, M, DMODEL, RP);
        ln_k<<<dim3(T_SEQ), dim3(256), 0, stream>>>(x, ln2_w + l * DMODEL, ln2_b + l * DMODEL, hbuf);
        gemm_t<64, 64, 0><<<dim3((M / 64) * (RF / 64)), dim3(256), 0, stream>>>(
            hbuf, w1V + (size_t)l * RF * DMODEL, f1_z + (size_t)l * RF,
            t1, nullptr, M, RF, DMODEL);
        gemm_t<128, 128, 1><<<dim3((M / 128) * (FFDIM / 128)), dim3(256), 0, stream>>>(
            t1, w1U + (size_t)l * FFDIM * RF, nullptr,
            ffb, nullptr, M, FFDIM, RF);
        gemm_t<64, 64, 0><<<dim3((M / 64) * (RF / 64)), dim3(256), 0, stream>>>(
            ffb, w2V + (size_t)l * RF * FFDIM, f2_z + (size_t)l * RF,
            t1, nullptr, M, RF, FFDIM);
        gemm_t<128, 128, 2><<<dim3((M / 128) * (DMODEL / 128)), dim3(256), 0, stream>>>(
            t1, w2U + (size_t)l * DMODEL * RF, nullptr,
            nullptr, x, M, DMODEL, RF);
    }
    ln_k<<<dim3(T_SEQ), dim3(256), 0, stream>>>(x, lnf_w, lnf_b, hbuf);
    gemm_t<128, 128, 3><<<dim3((M / 128) * (VOCAB / 128)), dim3(256), 0, stream>>>(
        hbuf, wlm, nullptr, nullptr, (float*)d_out, M, VOCAB, DMODEL);
}

// Round 11
// 1199.363 us; speedup vs baseline: 1.1616x; 1.0990x over previous
//
#include <hip/hip_runtime.h>
#include <hip/hip_bf16.h>

// ---------------------------------------------------------------------------
// TransformerSquared forward on MI355X.
// R10 = R9 passing base + attention operand re-tiling: K and V^T stored in
// fragment-order chunk layout so every attn_k kf/vf load is one coalesced
// 1KB wave-load (was a 16-segment gather). attn_k math unchanged.
// ---------------------------------------------------------------------------

#define T_SEQ 2048
#define DMODEL 1024
#define NHEAD 16
#define HSZ 64
#define NLAYER 4
#define FFDIM 4096
#define RH 16
#define RP 256
#define RF 256
#define VOCAB 32000
#define NKQV (3 * NHEAD * RH) // 768

typedef short short8 __attribute__((ext_vector_type(8)));
typedef float f32x4 __attribute__((ext_vector_type(4)));
typedef unsigned int uint_t;
typedef unsigned short ushort_t;

__device__ __forceinline__ float bfbits2f(uint_t bits16_in_low) {
    uint_t b = bits16_in_low << 16;
    float f;
    __builtin_memcpy(&f, &b, 4);
    return f;
}
__device__ __forceinline__ ushort_t f2bfu(float f) {
    union { __hip_bfloat16 b; ushort_t u; } cv;
    cv.b = __float2bfloat16(f);
    return cv.u;
}
__device__ __forceinline__ uint_t pack2bf(float a, float b) {
    return (uint_t)f2bfu(a) | ((uint_t)f2bfu(b) << 16);
}

// async global->LDS, 16 bytes per lane. LDS dest = wave-uniform base + lane*16.
__device__ __forceinline__ void gld16(const __hip_bfloat16* g, short* l) {
    __builtin_amdgcn_global_load_lds(
        (const __attribute__((address_space(1))) void*)g,
        (__attribute__((address_space(3))) void*)l, 16, 0, 0);
}

// ------------------------------- f32 -> bf16 -------------------------------
__global__ __launch_bounds__(256) void cvt_k(const float* __restrict__ in,
                                             __hip_bfloat16* __restrict__ out, int n4) {
    int i = blockIdx.x * 256 + threadIdx.x;
    if (i >= n4) return;
    float4 v = ((const float4*)in)[i];
    ushort4 o;
    o.x = f2bfu(v.x); o.y = f2bfu(v.y); o.z = f2bfu(v.z); o.w = f2bfu(v.w);
    ((ushort4*)out)[i] = o;
}

// ------------------------------- embedding ---------------------------------
__global__ __launch_bounds__(256) void embed_k(const int* __restrict__ idx,
                                               const float* __restrict__ tok,
                                               const float* __restrict__ pos,
                                               float* __restrict__ x) {
    int i = blockIdx.x * 256 + threadIdx.x;          // over T*D/4
    int d4 = i & (DMODEL / 4 - 1);
    int t = i >> 8;                                   // D/4 = 256
    int tk = idx[t];
    float4 a = ((const float4*)(tok + (size_t)tk * DMODEL))[d4];
    float4 p = ((const float4*)(pos + (size_t)t * DMODEL))[d4];
    a.x += p.x; a.y += p.y; a.z += p.z; a.w += p.w;
    ((float4*)(x + (size_t)t * DMODEL))[d4] = a;
}

// ------------------------------- layernorm ---------------------------------
__global__ __launch_bounds__(256) void ln_k(const float* __restrict__ xin,
                                            const float* __restrict__ w,
                                            const float* __restrict__ b,
                                            __hip_bfloat16* __restrict__ out) {
    const int row = blockIdx.x, tid = threadIdx.x;
    const float4 v = ((const float4*)(xin + (size_t)row * DMODEL))[tid];
    float s = v.x + v.y + v.z + v.w;
    float q = v.x * v.x + v.y * v.y + v.z * v.z + v.w * v.w;
    for (int off = 32; off; off >>= 1) { s += __shfl_xor(s, off); q += __shfl_xor(q, off); }
    __shared__ float rs_[4], rq_[4];
    if ((tid & 63) == 0) { rs_[tid >> 6] = s; rq_[tid >> 6] = q; }
    __syncthreads();
    s = rs_[0] + rs_[1] + rs_[2] + rs_[3];
    q = rq_[0] + rq_[1] + rq_[2] + rq_[3];
    const float mean = s * (1.f / DMODEL);
    const float var = q * (1.f / DMODEL) - mean * mean;
    const float rstd = rsqrtf(var + 1e-5f);
    const float4 wv = ((const float4*)w)[tid];
    const float4 bv = ((const float4*)b)[tid];
    ushort4 o;
    o.x = f2bfu((v.x - mean) * rstd * wv.x + bv.x);
    o.y = f2bfu((v.y - mean) * rstd * wv.y + bv.y);
    o.z = f2bfu((v.z - mean) * rstd * wv.z + bv.z);
    o.w = f2bfu((v.w - mean) * rstd * wv.w + bv.w);
    ((ushort4*)out)[(size_t)row * (DMODEL / 4) + tid] = o;
}

// --------------------------- generic GEMM (A * B^T) ------------------------
// m97-structure, 2-barrier, both-sides XOR swizzle (verified 0 conflicts R4).
template <int BM, int BN, int MODE>
__global__ __launch_bounds__(256) void gemm_t(const __hip_bfloat16* __restrict__ A,
                                              const __hip_bfloat16* __restrict__ B,
                                              const float* __restrict__ colscale,
                                              __hip_bfloat16* __restrict__ Cb,
                                              float* __restrict__ Cf,
                                              int M, int N, int K) {
    constexpr int WM = (BN >= 128) ? 2 : 4;
    constexpr int WN = 4 / WM;
    constexpr int TM = BM / WM / 16;
    constexpr int TN = BN / WN / 16;
    constexpr int IA = BM / 32;     // gld16 iters for A tile
    constexpr int IB = BN / 32;
    __shared__ short As[BM * 64];
    __shared__ short Bs[BN * 64];
    const int tid = threadIdx.x;
    const int w = tid >> 6, ln = tid & 63, lr = ln & 15, lg = ln >> 4;
    const int GM = M / BM;

    const int nwg = gridDim.x;
    const int cpx = nwg >> 3;
    const int wg = (blockIdx.x & 7) * cpx + (blockIdx.x >> 3);
    const int bm = wg % GM, bn = wg / GM;
    const int wm = w / WN, wn = w % WN;

    f32x4 acc[TM][TN] = {};

    const int srow = tid >> 3;
    const int scol = (((tid & 7) ^ ((tid >> 3) & 7)) * 8);
    const __hip_bfloat16* Ag = A + (size_t)(bm * BM + srow) * K + scol;
    const __hip_bfloat16* Bg = B + (size_t)(bn * BN + srow) * K + scol;

    for (int kt = 0; kt < K; kt += 64) {
        __syncthreads();   // previous tile consumed
#pragma unroll
        for (int i = 0; i < IA; ++i)
            gld16(Ag + (size_t)(i * 32) * K + kt, &As[i * 2048 + w * 512]);
#pragma unroll
        for (int i = 0; i < IB; ++i)
            gld16(Bg + (size_t)(i * 32) * K + kt, &Bs[i * 2048 + w * 512]);
        __syncthreads();   // drains vmcnt + barrier

#pragma unroll
        for (int kk = 0; kk < 2; ++kk) {
            short8 af[TM], bf[TN];
#pragma unroll
            for (int m = 0; m < TM; ++m) {
                const int row = wm * (BM / WM) + m * 16 + lr;
                af[m] = *(const short8*)&As[row * 64 + (((kk * 4 + lg) ^ (lr & 7)) * 8)];
            }
#pragma unroll
            for (int n = 0; n < TN; ++n) {
                const int row = wn * (BN / WN) + n * 16 + lr;
                bf[n] = *(const short8*)&Bs[row * 64 + (((kk * 4 + lg) ^ (lr & 7)) * 8)];
            }
#pragma unroll
            for (int m = 0; m < TM; ++m)
#pragma unroll
                for (int n = 0; n < TN; ++n)
                    acc[m][n] = __builtin_amdgcn_mfma_f32_16x16x32_bf16(af[m], bf[n], acc[m][n], 0, 0, 0);
        }
    }

#pragma unroll
    for (int n = 0; n < TN; ++n) {
        const int col = bn * BN + wn * (BN / WN) + n * 16 + lr;
        float cs = 1.0f;
        if (MODE == 0 && colscale) cs = colscale[col];
#pragma unroll
        for (int m = 0; m < TM; ++m) {
#pragma unroll
            for (int rr = 0; rr < 4; ++rr) {
                const int row = bm * BM + wm * (BM / WM) + m * 16 + lg * 4 + rr;
                float v = acc[m][n][rr];
                const size_t o = (size_t)row * N + col;
                if (MODE == 0) {
                    Cb[o] = __float2bfloat16(v * cs);
                } else if (MODE == 1) {
                    v = 0.5f * v * (1.0f + erff(v * 0.70710678118654752f));
                    Cb[o] = __float2bfloat16(v);
                } else if (MODE == 2) {
                    Cf[o] += v;
                } else {
                    Cf[o] = v;
                }
            }
        }
    }
}

// ----------------------- per-head SVF U-projection (K=16) ------------------
__global__ __launch_bounds__(256) void kqv2_k(const __hip_bfloat16* __restrict__ t1,
                                              const __hip_bfloat16* __restrict__ U,
                                              __hip_bfloat16* __restrict__ kqv) {
    size_t i = (size_t)blockIdx.x * 256 + threadIdx.x; // 3*16*2048*64
    int s = (int)(i & 63);
    size_t rest = i >> 6;
    int t = (int)(rest & (T_SEQ - 1));
    int gh = (int)(rest >> 11);
    const short8* trow = (const short8*)(t1 + (size_t)t * NKQV + gh * RH);
    const short8* urow = (const short8*)(U + ((size_t)gh * HSZ + s) * RH);
    short8 ta = trow[0], tb = trow[1];
    short8 ua = urow[0], ub = urow[1];
    float acc = 0.f;
#pragma unroll
    for (int j = 0; j < 8; ++j) {
        acc += bfbits2f((ushort_t)ta[j]) * bfbits2f((ushort_t)ua[j]);
        acc += bfbits2f((ushort_t)tb[j]) * bfbits2f((ushort_t)ub[j]);
    }
    kqv[i] = __float2bfloat16(acc);
}

// --------------------- K re-tile into fragment-chunk layout ----------------
// kb:  [h][t][d] row-major.  kb2: [h][tile][c=g*2+half][ln*8+j] where the
// value at (c, ln, j) = K[tile*64 + g*16 + (ln&15)][half*32 + (ln>>4)*8 + j].
// Reader (attn_k) lane ln then gets its whole fragment as one coalesced 16B.
__global__ __launch_bounds__(256) void ktile_k(const __hip_bfloat16* __restrict__ kb,
                                               __hip_bfloat16* __restrict__ kb2) {
    const int it = blockIdx.x, h = blockIdx.y, tid = threadIdx.x;
    const int wv = tid >> 6, ln = tid & 63;
    const int lr = ln & 15, lg = ln >> 4;
#pragma unroll
    for (int q2 = 0; q2 < 2; ++q2) {
        const int c = wv * 2 + q2, g = c >> 1, half = c & 1;
        short8 v = *(const short8*)(kb + ((size_t)h * T_SEQ + it * 64 + g * 16 + lr) * HSZ + half * 32 + lg * 8);
        *(short8*)(kb2 + (((size_t)h * 32 + it) * 8 + c) * 512 + (size_t)ln * 8) = v;
    }
}

// ----------------- V transpose + re-tile into fragment chunks --------------
// vb: [h][t][d]  ->  vt2 chunks: value(c=dt*2+half, ln, j) =
//   V^T[dt*16 + (ln&15)][tile*64 + half*32 + (ln>>4)*8 + j]
__global__ __launch_bounds__(256) void vtrans_k(const __hip_bfloat16* __restrict__ vb,
                                                __hip_bfloat16* __restrict__ vt2) {
    __shared__ short Ts[64][72];
    const int ti = blockIdx.x, h = blockIdx.y, tid = threadIdx.x;
    const int tl = tid >> 2, sc = (tid & 3) * 16;
    const short* src = (const short*)(vb + ((size_t)h * T_SEQ + ti * 64 + tl) * HSZ + sc);
    short8 a = ((const short8*)src)[0];
    short8 b = ((const short8*)src)[1];
#pragma unroll
    for (int j = 0; j < 8; ++j) { Ts[sc + j][tl] = a[j]; Ts[sc + 8 + j][tl] = b[j]; }
    __syncthreads();
    // write chunk layout: Ts[d][u_local] = V^T[d][u]
    const int c = tid >> 5, r5 = tid & 31;
    const int dt = c >> 1, half = c & 1;
#pragma unroll
    for (int k2 = 0; k2 < 2; ++k2) {
        const int ln2 = r5 * 2 + k2;
        const int d = dt * 16 + (ln2 & 15);
        const int ub = half * 32 + ((ln2 >> 4) * 8);
        short8 o;
#pragma unroll
        for (int j = 0; j < 8; ++j) o[j] = Ts[d][ub + j];
        *(short8*)(vt2 + (((size_t)h * 32 + ti) * 8 + c) * 512 + (size_t)ln2 * 8) = o;
    }
}

// --------------------------- MFMA flash attention --------------------------
// 1 wave = 16 q rows, KVBLK = 64 keys/iter. Block = 4 waves, strided q tiles.
// R9 bijective head-cluster remap kept. R10: kf/vf loads from chunk-tiled
// kb2/vt2 — each fragment load is one coalesced 1KB wave-load.
__global__ __launch_bounds__(256) void attn_k(const __hip_bfloat16* __restrict__ qb,
                                              const __hip_bfloat16* __restrict__ kb2,
                                              const __hip_bfloat16* __restrict__ vt2,
                                              __hip_bfloat16* __restrict__ attout) {
    __shared__ short P_s[2][4][16 * 72];  // [dbuf][wave][16 q x 64 u], stride 72
    const int tid = threadIdx.x, w = tid >> 6, ln = tid & 63;
    const int lr = ln & 15, lg = ln >> 4;
    const int f = blockIdx.y * 32 + blockIdx.x;
    const int h = ((f & 7) << 1) | ((f >> 3) & 1);
    const int bi = f >> 4;
    const int t0 = bi * 16 + w * 512;
    const size_t hb = (size_t)h * T_SEQ;
    const size_t hB = (size_t)h * 32;   // tile base for chunk addressing

    short8 qf0 = *(const short8*)(qb + (hb + t0 + lr) * HSZ + lg * 8);
    short8 qf1 = *(const short8*)(qb + (hb + t0 + lr) * HSZ + 32 + lg * 8);

    f32x4 acc[4] = {};
    float mrun = -3e38f, lrun = 0.f;
    int pbuf = 0;

    short8 kf[4][2];
#pragma unroll
    for (int g = 0; g < 4; ++g) {
        kf[g][0] = *(const short8*)(kb2 + (hB * 8 + g * 2 + 0) * 512 + (size_t)ln * 8);
        kf[g][1] = *(const short8*)(kb2 + (hB * 8 + g * 2 + 1) * 512 + (size_t)ln * 8);
    }

    for (int u0 = 0; u0 <= t0 + 15; u0 += 64) {
        const int it = u0 >> 6;
        f32x4 st[4];
#pragma unroll
        for (int g = 0; g < 4; ++g) {
            f32x4 z = {};
            z = __builtin_amdgcn_mfma_f32_16x16x32_bf16(kf[g][0], qf0, z, 0, 0, 0);
            st[g] = __builtin_amdgcn_mfma_f32_16x16x32_bf16(kf[g][1], qf1, z, 0, 0, 0);
        }

        const int un = u0 + 64;
        if (un <= t0 + 15) {
            const int itn = it + 1;
#pragma unroll
            for (int g = 0; g < 4; ++g) {
                kf[g][0] = *(const short8*)(kb2 + ((hB + itn) * 8 + g * 2 + 0) * 512 + (size_t)ln * 8);
                kf[g][1] = *(const short8*)(kb2 + ((hB + itn) * 8 + g * 2 + 1) * 512 + (size_t)ln * 8);
            }
        }
        short8 vf[4][2];
#pragma unroll
        for (int dt = 0; dt < 4; ++dt) {
            vf[dt][0] = *(const short8*)(vt2 + ((hB + it) * 8 + dt * 2 + 0) * 512 + (size_t)ln * 8);
            vf[dt][1] = *(const short8*)(vt2 + ((hB + it) * 8 + dt * 2 + 1) * 512 + (size_t)ln * 8);
        }

        const int qg = t0 + lr;
        float sv[16];
#pragma unroll
        for (int g = 0; g < 4; ++g) {
            const bool needm = (u0 + g * 16 + 15 > t0);
#pragma unroll
            for (int r = 0; r < 4; ++r) {
                float v = st[g][r] * 0.125f;
                if (needm && (u0 + g * 16 + lg * 4 + r > qg)) v = -1e30f;
                sv[g * 4 + r] = v;
            }
        }
        float tm = sv[0];
#pragma unroll
        for (int j = 1; j < 16; ++j) tm = fmaxf(tm, sv[j]);
        tm = fmaxf(tm, __shfl_xor(tm, 16));
        tm = fmaxf(tm, __shfl_xor(tm, 32));
        const float mnew = fmaxf(mrun, tm);
        const float corr = __expf(mrun - mnew);
        float pv[16];
        float ls = 0.f;
#pragma unroll
        for (int j = 0; j < 16; ++j) { pv[j] = __expf(sv[j] - mnew); ls += pv[j]; }
        ls += __shfl_xor(ls, 16);
        ls += __shfl_xor(ls, 32);
        lrun = lrun * corr + ls;
#pragma unroll
        for (int dt = 0; dt < 4; ++dt) acc[dt] *= corr;

        uint_t* pw = (uint_t*)P_s[pbuf][w];
        const int wb = lr * 36 + lg * 2;
#pragma unroll
        for (int g = 0; g < 4; ++g) {
            pw[wb + g * 8 + 0] = pack2bf(pv[g * 4 + 0], pv[g * 4 + 1]);
            pw[wb + g * 8 + 1] = pack2bf(pv[g * 4 + 2], pv[g * 4 + 3]);
        }
        asm volatile("s_waitcnt lgkmcnt(0)" ::: "memory");
        short8 pf0 = *(const short8*)(&P_s[pbuf][w][lr * 72 + lg * 8]);
        short8 pf1 = *(const short8*)(&P_s[pbuf][w][lr * 72 + 32 + lg * 8]);

#pragma unroll
        for (int dt = 0; dt < 4; ++dt) {
            acc[dt] = __builtin_amdgcn_mfma_f32_16x16x32_bf16(vf[dt][0], pf0, acc[dt], 0, 0, 0);
            acc[dt] = __builtin_amdgcn_mfma_f32_16x16x32_bf16(vf[dt][1], pf1, acc[dt], 0, 0, 0);
        }

        mrun = mnew;
        pbuf ^= 1;
    }

    const float inv = 1.f / lrun;
#pragma unroll
    for (int dt = 0; dt < 4; ++dt) {
#pragma unroll
        for (int r = 0; r < 4; r += 2) {
            uint_t pk = pack2bf(acc[dt][r] * inv, acc[dt][r + 1] * inv);
            *(uint_t*)(attout + (size_t)(t0 + lr) * DMODEL + h * HSZ + dt * 16 + lg * 4 + r) = pk;
        }
    }
}

// ---------------------------------------------------------------------------
extern "C" void kernel_launch(void* const* d_in, const int* in_sizes, int n_in,
                              void* d_out, int out_size, void* d_ws, size_t ws_size,
                              hipStream_t stream) {
    const int* idx = (const int*)d_in[0];
    const float* tok_emb = (const float*)d_in[1];
    const float* pos_emb = (const float*)d_in[2];
    const float* ln1_w = (const float*)d_in[3];
    const float* ln1_b = (const float*)d_in[4];
    const float* ln2_w = (const float*)d_in[5];
    const float* ln2_b = (const float*)d_in[6];
    const float* kqv_V = (const float*)d_in[7];
    const float* kqv_z = (const float*)d_in[8];
    const float* kqv_U = (const float*)d_in[9];
    const float* proj_V = (const float*)d_in[10];
    const float* proj_z = (const float*)d_in[11];
    const float* proj_U = (const float*)d_in[12];
    const float* f1_V = (const float*)d_in[13];
    const float* f1_z = (const float*)d_in[14];
    const float* f1_U = (const float*)d_in[15];
    const float* f2_V = (const float*)d_in[16];
    const float* f2_z = (const float*)d_in[17];
    const float* f2_U = (const float*)d_in[18];
    const float* lnf_w = (const float*)d_in[19];
    const float* lnf_b = (const float*)d_in[20];
    const float* lm_w = (const float*)d_in[21];

    // ---------------- workspace layout ----------------
    char* W = (char*)d_ws;
    float* x = (float*)W;                 W += (size_t)T_SEQ * DMODEL * 4;
    __hip_bfloat16* hbuf = (__hip_bfloat16*)W; W += (size_t)T_SEQ * DMODEL * 2;
    __hip_bfloat16* t1 = (__hip_bfloat16*)W;   W += (size_t)T_SEQ * NKQV * 2;
    __hip_bfloat16* kqvb = (__hip_bfloat16*)W; W += (size_t)3 * NHEAD * T_SEQ * HSZ * 2;
    __hip_bfloat16* kb2 = (__hip_bfloat16*)W;  W += (size_t)NHEAD * T_SEQ * HSZ * 2;  // K chunk-tiled
    __hip_bfloat16* vt2 = (__hip_bfloat16*)W;  W += (size_t)NHEAD * HSZ * T_SEQ * 2;  // V^T chunk-tiled
    __hip_bfloat16* attb = (__hip_bfloat16*)W; W += (size_t)T_SEQ * DMODEL * 2;
    __hip_bfloat16* ffb = (__hip_bfloat16*)W;  W += (size_t)T_SEQ * FFDIM * 2;
    __hip_bfloat16* wkV = (__hip_bfloat16*)W;  W += (size_t)NLAYER * NKQV * DMODEL * 2;
    __hip_bfloat16* wkU = (__hip_bfloat16*)W;  W += (size_t)NLAYER * 3 * NHEAD * HSZ * RH * 2;
    __hip_bfloat16* wpV = (__hip_bfloat16*)W;  W += (size_t)NLAYER * RP * DMODEL * 2;
    __hip_bfloat16* wpU = (__hip_bfloat16*)W;  W += (size_t)NLAYER * DMODEL * RP * 2;
    __hip_bfloat16* w1V = (__hip_bfloat16*)W;  W += (size_t)NLAYER * RF * DMODEL * 2;
    __hip_bfloat16* w1U = (__hip_bfloat16*)W;  W += (size_t)NLAYER * FFDIM * RF * 2;
    __hip_bfloat16* w2V = (__hip_bfloat16*)W;  W += (size_t)NLAYER * RF * FFDIM * 2;
    __hip_bfloat16* w2U = (__hip_bfloat16*)W;  W += (size_t)NLAYER * DMODEL * RF * 2;
    __hip_bfloat16* wlm = (__hip_bfloat16*)W;  W += (size_t)VOCAB * DMODEL * 2;

    auto cvt = [&](const float* src, __hip_bfloat16* dst, size_t n) {
        int n4 = (int)(n / 4);
        cvt_k<<<dim3((n4 + 255) / 256), dim3(256), 0, stream>>>(src, dst, n4);
    };
    cvt(kqv_V, wkV, (size_t)NLAYER * NKQV * DMODEL);
    cvt(kqv_U, wkU, (size_t)NLAYER * 3 * NHEAD * HSZ * RH);
    cvt(proj_V, wpV, (size_t)NLAYER * RP * DMODEL);
    cvt(proj_U, wpU, (size_t)NLAYER * DMODEL * RP);
    cvt(f1_V, w1V, (size_t)NLAYER * RF * DMODEL);
    cvt(f1_U, w1U, (size_t)NLAYER * FFDIM * RF);
    cvt(f2_V, w2V, (size_t)NLAYER * RF * FFDIM);
    cvt(f2_U, w2U, (size_t)NLAYER * DMODEL * RF);
    cvt(lm_w, wlm, (size_t)VOCAB * DMODEL);

    embed_k<<<dim3(T_SEQ * DMODEL / 4 / 256), dim3(256), 0, stream>>>(idx, tok_emb, pos_emb, x);

    const int M = T_SEQ;
    for (int l = 0; l < NLAYER; ++l) {
        ln_k<<<dim3(T_SEQ), dim3(256), 0, stream>>>(x, ln1_w + l * DMODEL, ln1_b + l * DMODEL, hbuf);
        gemm_t<64, 64, 0><<<dim3((M / 64) * (NKQV / 64)), dim3(256), 0, stream>>>(
            hbuf, wkV + (size_t)l * NKQV * DMODEL, kqv_z + (size_t)l * NKQV,
            t1, nullptr, M, NKQV, DMODEL);
        kqv2_k<<<dim3(3 * NHEAD * T_SEQ * HSZ / 256), dim3(256), 0, stream>>>(
            t1, wkU + (size_t)l * 3 * NHEAD * HSZ * RH, kqvb);
        {
            const __hip_bfloat16* kk = kqvb;
            const __hip_bfloat16* qq = kqvb + (size_t)NHEAD * T_SEQ * HSZ;
            const __hip_bfloat16* vv = kqvb + (size_t)2 * NHEAD * T_SEQ * HSZ;
            ktile_k<<<dim3(T_SEQ / 64, NHEAD), dim3(256), 0, stream>>>(kk, kb2);
            vtrans_k<<<dim3(T_SEQ / 64, NHEAD), dim3(256), 0, stream>>>(vv, vt2);
            attn_k<<<dim3(T_SEQ / 64, NHEAD), dim3(256), 0, stream>>>(qq, kb2, vt2, attb);
        }
        gemm_t<64, 64, 0><<<dim3((M / 64) * (RP / 64)), dim3(256), 0, stream>>>(
            attb, wpV + (size_t)l * RP * DMODEL, proj_z + (size_t)l * RP,
            t1, nullptr, M, RP, DMODEL);
        gemm_t<128, 128, 2><<<dim3((M / 128) * (DMODEL / 128)), dim3(256), 0, stream>>>(
            t1, wpU + (size_t)l * DMODEL * RP, nullptr,
            nullptr, x, M, DMODEL, RP);
        ln_k<<<dim3(T_SEQ), dim3(256), 0, stream>>>(x, ln2_w + l * DMODEL, ln2_b + l * DMODEL, hbuf);
        gemm_t<64, 64, 0><<<dim3((M / 64) * (RF / 64)), dim3(256), 0, stream>>>(
            hbuf, w1V + (size_t)l * RF * DMODEL, f1_z + (size_t)l * RF,
            t1, nullptr, M, RF, DMODEL);
        gemm_t<128, 128, 1><<<dim3((M / 128) * (FFDIM / 128)), dim3(256), 0, stream>>>(
            t1, w1U + (size_t)l * FFDIM * RF, nullptr,
            ffb, nullptr, M, FFDIM, RF);
        gemm_t<64, 64, 0><<<dim3((M / 64) * (RF / 64)), dim3(256), 0, stream>>>(
            ffb, w2V + (size_t)l * RF * FFDIM, f2_z + (size_t)l * RF,
            t1, nullptr, M, RF, FFDIM);
        gemm_t<128, 128, 2><<<dim3((M / 128) * (DMODEL / 128)), dim3(256), 0, stream>>>(
            t1, w2U + (size_t)l * DMODEL * RF, nullptr,
            nullptr, x, M, DMODEL, RF);
    }
    ln_k<<<dim3(T_SEQ), dim3(256), 0, stream>>>(x, lnf_w, lnf_b, hbuf);
    gemm_t<128, 128, 3><<<dim3((M / 128) * (VOCAB / 128)), dim3(256), 0, stream>>>(
        hbuf, wlm, nullptr, nullptr, (float*)d_out, M, VOCAB, DMODEL);
}

// Round 12
// 1177.341 us; speedup vs baseline: 1.1834x; 1.0187x over previous
//
#include <hip/hip_runtime.h>
#include <hip/hip_bf16.h>

// ---------------------------------------------------------------------------
// TransformerSquared forward on MI355X.
// R11 = R10 base + (1) kqv2_k writes Q normally and K/V directly in the
// chunk-tiled fragment layouts (ktile_k/vtrans_k kernels removed),
// (2) single batched weight-convert kernel (9 launches -> 1),
// (3) attn softmax in exp2 domain (R4-verified).
// ---------------------------------------------------------------------------

#define T_SEQ 2048
#define DMODEL 1024
#define NHEAD 16
#define HSZ 64
#define NLAYER 4
#define FFDIM 4096
#define RH 16
#define RP 256
#define RF 256
#define VOCAB 32000
#define NKQV (3 * NHEAD * RH) // 768

typedef short short8 __attribute__((ext_vector_type(8)));
typedef float f32x4 __attribute__((ext_vector_type(4)));
typedef unsigned int uint_t;
typedef unsigned short ushort_t;

__device__ __forceinline__ float bfbits2f(uint_t bits16_in_low) {
    uint_t b = bits16_in_low << 16;
    float f;
    __builtin_memcpy(&f, &b, 4);
    return f;
}
__device__ __forceinline__ ushort_t f2bfu(float f) {
    union { __hip_bfloat16 b; ushort_t u; } cv;
    cv.b = __float2bfloat16(f);
    return cv.u;
}
__device__ __forceinline__ uint_t pack2bf(float a, float b) {
    return (uint_t)f2bfu(a) | ((uint_t)f2bfu(b) << 16);
}

// async global->LDS, 16 bytes per lane. LDS dest = wave-uniform base + lane*16.
__device__ __forceinline__ void gld16(const __hip_bfloat16* g, short* l) {
    __builtin_amdgcn_global_load_lds(
        (const __attribute__((address_space(1))) void*)g,
        (__attribute__((address_space(3))) void*)l, 16, 0, 0);
}

// ----------------------- batched f32 -> bf16 convert -----------------------
struct CvtArgs {
    const float* s[9];
    __hip_bfloat16* d[9];
    int n4[9];
};
__global__ __launch_bounds__(256) void cvtall_k(CvtArgs a, int total4) {
    int i = blockIdx.x * 256 + threadIdx.x;
    if (i >= total4) return;
#pragma unroll
    for (int k = 0; k < 9; ++k) {
        if (i < a.n4[k]) {
            float4 v = ((const float4*)a.s[k])[i];
            ushort4 o;
            o.x = f2bfu(v.x); o.y = f2bfu(v.y); o.z = f2bfu(v.z); o.w = f2bfu(v.w);
            ((ushort4*)a.d[k])[i] = o;
            return;
        }
        i -= a.n4[k];
    }
}

// ------------------------------- embedding ---------------------------------
__global__ __launch_bounds__(256) void embed_k(const int* __restrict__ idx,
                                               const float* __restrict__ tok,
                                               const float* __restrict__ pos,
                                               float* __restrict__ x) {
    int i = blockIdx.x * 256 + threadIdx.x;          // over T*D/4
    int d4 = i & (DMODEL / 4 - 1);
    int t = i >> 8;                                   // D/4 = 256
    int tk = idx[t];
    float4 a = ((const float4*)(tok + (size_t)tk * DMODEL))[d4];
    float4 p = ((const float4*)(pos + (size_t)t * DMODEL))[d4];
    a.x += p.x; a.y += p.y; a.z += p.z; a.w += p.w;
    ((float4*)(x + (size_t)t * DMODEL))[d4] = a;
}

// ------------------------------- layernorm ---------------------------------
__global__ __launch_bounds__(256) void ln_k(const float* __restrict__ xin,
                                            const float* __restrict__ w,
                                            const float* __restrict__ b,
                                            __hip_bfloat16* __restrict__ out) {
    const int row = blockIdx.x, tid = threadIdx.x;
    const float4 v = ((const float4*)(xin + (size_t)row * DMODEL))[tid];
    float s = v.x + v.y + v.z + v.w;
    float q = v.x * v.x + v.y * v.y + v.z * v.z + v.w * v.w;
    for (int off = 32; off; off >>= 1) { s += __shfl_xor(s, off); q += __shfl_xor(q, off); }
    __shared__ float rs_[4], rq_[4];
    if ((tid & 63) == 0) { rs_[tid >> 6] = s; rq_[tid >> 6] = q; }
    __syncthreads();
    s = rs_[0] + rs_[1] + rs_[2] + rs_[3];
    q = rq_[0] + rq_[1] + rq_[2] + rq_[3];
    const float mean = s * (1.f / DMODEL);
    const float var = q * (1.f / DMODEL) - mean * mean;
    const float rstd = rsqrtf(var + 1e-5f);
    const float4 wv = ((const float4*)w)[tid];
    const float4 bv = ((const float4*)b)[tid];
    ushort4 o;
    o.x = f2bfu((v.x - mean) * rstd * wv.x + bv.x);
    o.y = f2bfu((v.y - mean) * rstd * wv.y + bv.y);
    o.z = f2bfu((v.z - mean) * rstd * wv.z + bv.z);
    o.w = f2bfu((v.w - mean) * rstd * wv.w + bv.w);
    ((ushort4*)out)[(size_t)row * (DMODEL / 4) + tid] = o;
}

// --------------------------- generic GEMM (A * B^T) ------------------------
// m97-structure, 2-barrier, both-sides XOR swizzle (verified 0 conflicts R4).
template <int BM, int BN, int MODE>
__global__ __launch_bounds__(256) void gemm_t(const __hip_bfloat16* __restrict__ A,
                                              const __hip_bfloat16* __restrict__ B,
                                              const float* __restrict__ colscale,
                                              __hip_bfloat16* __restrict__ Cb,
                                              float* __restrict__ Cf,
                                              int M, int N, int K) {
    constexpr int WM = (BN >= 128) ? 2 : 4;
    constexpr int WN = 4 / WM;
    constexpr int TM = BM / WM / 16;
    constexpr int TN = BN / WN / 16;
    constexpr int IA = BM / 32;     // gld16 iters for A tile
    constexpr int IB = BN / 32;
    __shared__ short As[BM * 64];
    __shared__ short Bs[BN * 64];
    const int tid = threadIdx.x;
    const int w = tid >> 6, ln = tid & 63, lr = ln & 15, lg = ln >> 4;
    const int GM = M / BM;

    const int nwg = gridDim.x;
    const int cpx = nwg >> 3;
    const int wg = (blockIdx.x & 7) * cpx + (blockIdx.x >> 3);
    const int bm = wg % GM, bn = wg / GM;
    const int wm = w / WN, wn = w % WN;

    f32x4 acc[TM][TN] = {};

    const int srow = tid >> 3;
    const int scol = (((tid & 7) ^ ((tid >> 3) & 7)) * 8);
    const __hip_bfloat16* Ag = A + (size_t)(bm * BM + srow) * K + scol;
    const __hip_bfloat16* Bg = B + (size_t)(bn * BN + srow) * K + scol;

    for (int kt = 0; kt < K; kt += 64) {
        __syncthreads();   // previous tile consumed
#pragma unroll
        for (int i = 0; i < IA; ++i)
            gld16(Ag + (size_t)(i * 32) * K + kt, &As[i * 2048 + w * 512]);
#pragma unroll
        for (int i = 0; i < IB; ++i)
            gld16(Bg + (size_t)(i * 32) * K + kt, &Bs[i * 2048 + w * 512]);
        __syncthreads();   // drains vmcnt + barrier

#pragma unroll
        for (int kk = 0; kk < 2; ++kk) {
            short8 af[TM], bf[TN];
#pragma unroll
            for (int m = 0; m < TM; ++m) {
                const int row = wm * (BM / WM) + m * 16 + lr;
                af[m] = *(const short8*)&As[row * 64 + (((kk * 4 + lg) ^ (lr & 7)) * 8)];
            }
#pragma unroll
            for (int n = 0; n < TN; ++n) {
                const int row = wn * (BN / WN) + n * 16 + lr;
                bf[n] = *(const short8*)&Bs[row * 64 + (((kk * 4 + lg) ^ (lr & 7)) * 8)];
            }
#pragma unroll
            for (int m = 0; m < TM; ++m)
#pragma unroll
                for (int n = 0; n < TN; ++n)
                    acc[m][n] = __builtin_amdgcn_mfma_f32_16x16x32_bf16(af[m], bf[n], acc[m][n], 0, 0, 0);
        }
    }

#pragma unroll
    for (int n = 0; n < TN; ++n) {
        const int col = bn * BN + wn * (BN / WN) + n * 16 + lr;
        float cs = 1.0f;
        if (MODE == 0 && colscale) cs = colscale[col];
#pragma unroll
        for (int m = 0; m < TM; ++m) {
#pragma unroll
            for (int rr = 0; rr < 4; ++rr) {
                const int row = bm * BM + wm * (BM / WM) + m * 16 + lg * 4 + rr;
                float v = acc[m][n][rr];
                const size_t o = (size_t)row * N + col;
                if (MODE == 0) {
                    Cb[o] = __float2bfloat16(v * cs);
                } else if (MODE == 1) {
                    v = 0.5f * v * (1.0f + erff(v * 0.70710678118654752f));
                    Cb[o] = __float2bfloat16(v);
                } else if (MODE == 2) {
                    Cf[o] += v;
                } else {
                    Cf[o] = v;
                }
            }
        }
    }
}

// ------------- per-head SVF U-projection (K=16) + layout fusion ------------
// Computes kqv = (t1 @ U^T) per head; writes Q rows normally, K and V
// DIRECTLY in the chunk-tiled fragment layouts consumed by attn_k:
//   K elem (h,t,d): tile=t>>6, c=((t>>4)&3)*2+(d>>5), ln=((d>>3)&3)*16+(t&15),
//                   j=d&7  -> kb2[((h*32+tile)*8+c)*512 + ln*8 + j]
//   V elem (h,u,d): tile=u>>6, c=(d>>4)*2+((u>>5)&1), ln=((u>>3)&3)*16+(d&15),
//                   j=u&7  -> vt2[((h*32+tile)*8+c)*512 + ln*8 + j]
// (bijections verified against the R10 ktile_k/vtrans_k mappings)
__global__ __launch_bounds__(256) void kqv2_k(const __hip_bfloat16* __restrict__ t1,
                                              const __hip_bfloat16* __restrict__ U,
                                              __hip_bfloat16* __restrict__ qb,
                                              __hip_bfloat16* __restrict__ kb2,
                                              __hip_bfloat16* __restrict__ vt2) {
    size_t i = (size_t)blockIdx.x * 256 + threadIdx.x; // 3*16*2048*64
    int s = (int)(i & 63);
    size_t rest = i >> 6;
    int t = (int)(rest & (T_SEQ - 1));
    int gh = (int)(rest >> 11);                        // 0..47, g-major
    const short8* trow = (const short8*)(t1 + (size_t)t * NKQV + gh * RH);
    const short8* urow = (const short8*)(U + ((size_t)gh * HSZ + s) * RH);
    short8 ta = trow[0], tb = trow[1];
    short8 ua = urow[0], ub = urow[1];
    float acc = 0.f;
#pragma unroll
    for (int j = 0; j < 8; ++j) {
        acc += bfbits2f((ushort_t)ta[j]) * bfbits2f((ushort_t)ua[j]);
        acc += bfbits2f((ushort_t)tb[j]) * bfbits2f((ushort_t)ub[j]);
    }
    const ushort_t val = f2bfu(acc);
    const int g = gh >> 4, h = gh & 15;               // block-uniform g
    if (g == 1) {
        ((ushort_t*)qb)[((size_t)h * T_SEQ + t) * HSZ + s] = val;
    } else if (g == 0) {
        const int tile = t >> 6, gg = (t >> 4) & 3, lr = t & 15;
        const int half = s >> 5, lg = (s >> 3) & 3, j = s & 7;
        const int c = gg * 2 + half, ln = lg * 16 + lr;
        ((ushort_t*)kb2)[(((size_t)h * 32 + tile) * 8 + c) * 512 + ln * 8 + j] = val;
    } else {
        const int tile = t >> 6, half = (t >> 5) & 1, lg2 = (t >> 3) & 3, j2 = t & 7;
        const int dt = s >> 4, lr2 = s & 15;
        const int c = dt * 2 + half, ln = lg2 * 16 + lr2;
        ((ushort_t*)vt2)[(((size_t)h * 32 + tile) * 8 + c) * 512 + ln * 8 + j2] = val;
    }
}

// --------------------------- MFMA flash attention --------------------------
// 1 wave = 16 q rows, KVBLK = 64 keys/iter. Block = 4 waves, strided q tiles.
// R9 bijective head-cluster remap; R10 chunk-tiled coalesced operand loads;
// R11 softmax in exp2 domain (constant-folded scale, R4-verified).
__global__ __launch_bounds__(256) void attn_k(const __hip_bfloat16* __restrict__ qb,
                                              const __hip_bfloat16* __restrict__ kb2,
                                              const __hip_bfloat16* __restrict__ vt2,
                                              __hip_bfloat16* __restrict__ attout) {
    __shared__ short P_s[2][4][16 * 72];  // [dbuf][wave][16 q x 64 u], stride 72
    const int tid = threadIdx.x, w = tid >> 6, ln = tid & 63;
    const int lr = ln & 15, lg = ln >> 4;
    const int f = blockIdx.y * 32 + blockIdx.x;
    const int h = ((f & 7) << 1) | ((f >> 3) & 1);
    const int bi = f >> 4;
    const int t0 = bi * 16 + w * 512;
    const size_t hb = (size_t)h * T_SEQ;
    const size_t hB = (size_t)h * 32;   // tile base for chunk addressing
    const float SCL = 0.18033688011112042f; // 0.125 * log2(e)

    short8 qf0 = *(const short8*)(qb + (hb + t0 + lr) * HSZ + lg * 8);
    short8 qf1 = *(const short8*)(qb + (hb + t0 + lr) * HSZ + 32 + lg * 8);

    f32x4 acc[4] = {};
    float mrun = -3e38f, lrun = 0.f;
    int pbuf = 0;

    short8 kf[4][2];
#pragma unroll
    for (int g = 0; g < 4; ++g) {
        kf[g][0] = *(const short8*)(kb2 + (hB * 8 + g * 2 + 0) * 512 + (size_t)ln * 8);
        kf[g][1] = *(const short8*)(kb2 + (hB * 8 + g * 2 + 1) * 512 + (size_t)ln * 8);
    }

    for (int u0 = 0; u0 <= t0 + 15; u0 += 64) {
        const int it = u0 >> 6;
        f32x4 st[4];
#pragma unroll
        for (int g = 0; g < 4; ++g) {
            f32x4 z = {};
            z = __builtin_amdgcn_mfma_f32_16x16x32_bf16(kf[g][0], qf0, z, 0, 0, 0);
            st[g] = __builtin_amdgcn_mfma_f32_16x16x32_bf16(kf[g][1], qf1, z, 0, 0, 0);
        }

        const int un = u0 + 64;
        if (un <= t0 + 15) {
            const int itn = it + 1;
#pragma unroll
            for (int g = 0; g < 4; ++g) {
                kf[g][0] = *(const short8*)(kb2 + ((hB + itn) * 8 + g * 2 + 0) * 512 + (size_t)ln * 8);
                kf[g][1] = *(const short8*)(kb2 + ((hB + itn) * 8 + g * 2 + 1) * 512 + (size_t)ln * 8);
            }
        }
        short8 vf[4][2];
#pragma unroll
        for (int dt = 0; dt < 4; ++dt) {
            vf[dt][0] = *(const short8*)(vt2 + ((hB + it) * 8 + dt * 2 + 0) * 512 + (size_t)ln * 8);
            vf[dt][1] = *(const short8*)(vt2 + ((hB + it) * 8 + dt * 2 + 1) * 512 + (size_t)ln * 8);
        }

        const int qg = t0 + lr;
        float sv[16];
#pragma unroll
        for (int g = 0; g < 4; ++g) {
            const bool needm = (u0 + g * 16 + 15 > t0);
#pragma unroll
            for (int r = 0; r < 4; ++r) {
                float v = st[g][r] * SCL;
                if (needm && (u0 + g * 16 + lg * 4 + r > qg)) v = -1e30f;
                sv[g * 4 + r] = v;
            }
        }
        float tm = sv[0];
#pragma unroll
        for (int j = 1; j < 16; ++j) tm = fmaxf(tm, sv[j]);
        tm = fmaxf(tm, __shfl_xor(tm, 16));
        tm = fmaxf(tm, __shfl_xor(tm, 32));
        const float mnew = fmaxf(mrun, tm);
        const float corr = exp2f(mrun - mnew);
        float pv[16];
        float ls = 0.f;
#pragma unroll
        for (int j = 0; j < 16; ++j) { pv[j] = exp2f(sv[j] - mnew); ls += pv[j]; }
        ls += __shfl_xor(ls, 16);
        ls += __shfl_xor(ls, 32);
        lrun = lrun * corr + ls;
#pragma unroll
        for (int dt = 0; dt < 4; ++dt) acc[dt] *= corr;

        uint_t* pw = (uint_t*)P_s[pbuf][w];
        const int wb = lr * 36 + lg * 2;
#pragma unroll
        for (int g = 0; g < 4; ++g) {
            pw[wb + g * 8 + 0] = pack2bf(pv[g * 4 + 0], pv[g * 4 + 1]);
            pw[wb + g * 8 + 1] = pack2bf(pv[g * 4 + 2], pv[g * 4 + 3]);
        }
        asm volatile("s_waitcnt lgkmcnt(0)" ::: "memory");
        short8 pf0 = *(const short8*)(&P_s[pbuf][w][lr * 72 + lg * 8]);
        short8 pf1 = *(const short8*)(&P_s[pbuf][w][lr * 72 + 32 + lg * 8]);

#pragma unroll
        for (int dt = 0; dt < 4; ++dt) {
            acc[dt] = __builtin_amdgcn_mfma_f32_16x16x32_bf16(vf[dt][0], pf0, acc[dt], 0, 0, 0);
            acc[dt] = __builtin_amdgcn_mfma_f32_16x16x32_bf16(vf[dt][1], pf1, acc[dt], 0, 0, 0);
        }

        mrun = mnew;
        pbuf ^= 1;
    }

    const float inv = 1.f / lrun;
#pragma unroll
    for (int dt = 0; dt < 4; ++dt) {
#pragma unroll
        for (int r = 0; r < 4; r += 2) {
            uint_t pk = pack2bf(acc[dt][r] * inv, acc[dt][r + 1] * inv);
            *(uint_t*)(attout + (size_t)(t0 + lr) * DMODEL + h * HSZ + dt * 16 + lg * 4 + r) = pk;
        }
    }
}

// ---------------------------------------------------------------------------
extern "C" void kernel_launch(void* const* d_in, const int* in_sizes, int n_in,
                              void* d_out, int out_size, void* d_ws, size_t ws_size,
                              hipStream_t stream) {
    const int* idx = (const int*)d_in[0];
    const float* tok_emb = (const float*)d_in[1];
    const float* pos_emb = (const float*)d_in[2];
    const float* ln1_w = (const float*)d_in[3];
    const float* ln1_b = (const float*)d_in[4];
    const float* ln2_w = (const float*)d_in[5];
    const float* ln2_b = (const float*)d_in[6];
    const float* kqv_V = (const float*)d_in[7];
    const float* kqv_z = (const float*)d_in[8];
    const float* kqv_U = (const float*)d_in[9];
    const float* proj_V = (const float*)d_in[10];
    const float* proj_z = (const float*)d_in[11];
    const float* proj_U = (const float*)d_in[12];
    const float* f1_V = (const float*)d_in[13];
    const float* f1_z = (const float*)d_in[14];
    const float* f1_U = (const float*)d_in[15];
    const float* f2_V = (const float*)d_in[16];
    const float* f2_z = (const float*)d_in[17];
    const float* f2_U = (const float*)d_in[18];
    const float* lnf_w = (const float*)d_in[19];
    const float* lnf_b = (const float*)d_in[20];
    const float* lm_w = (const float*)d_in[21];

    // ---------------- workspace layout ----------------
    char* W = (char*)d_ws;
    float* x = (float*)W;                 W += (size_t)T_SEQ * DMODEL * 4;
    __hip_bfloat16* hbuf = (__hip_bfloat16*)W; W += (size_t)T_SEQ * DMODEL * 2;
    __hip_bfloat16* t1 = (__hip_bfloat16*)W;   W += (size_t)T_SEQ * NKQV * 2;
    __hip_bfloat16* qbuf = (__hip_bfloat16*)W; W += (size_t)NHEAD * T_SEQ * HSZ * 2;  // Q rows
    __hip_bfloat16* kb2 = (__hip_bfloat16*)W;  W += (size_t)NHEAD * T_SEQ * HSZ * 2;  // K chunk-tiled
    __hip_bfloat16* vt2 = (__hip_bfloat16*)W;  W += (size_t)NHEAD * HSZ * T_SEQ * 2;  // V^T chunk-tiled
    __hip_bfloat16* attb = (__hip_bfloat16*)W; W += (size_t)T_SEQ * DMODEL * 2;
    __hip_bfloat16* ffb = (__hip_bfloat16*)W;  W += (size_t)T_SEQ * FFDIM * 2;
    __hip_bfloat16* wkV = (__hip_bfloat16*)W;  W += (size_t)NLAYER * NKQV * DMODEL * 2;
    __hip_bfloat16* wkU = (__hip_bfloat16*)W;  W += (size_t)NLAYER * 3 * NHEAD * HSZ * RH * 2;
    __hip_bfloat16* wpV = (__hip_bfloat16*)W;  W += (size_t)NLAYER * RP * DMODEL * 2;
    __hip_bfloat16* wpU = (__hip_bfloat16*)W;  W += (size_t)NLAYER * DMODEL * RP * 2;
    __hip_bfloat16* w1V = (__hip_bfloat16*)W;  W += (size_t)NLAYER * RF * DMODEL * 2;
    __hip_bfloat16* w1U = (__hip_bfloat16*)W;  W += (size_t)NLAYER * FFDIM * RF * 2;
    __hip_bfloat16* w2V = (__hip_bfloat16*)W;  W += (size_t)NLAYER * RF * FFDIM * 2;
    __hip_bfloat16* w2U = (__hip_bfloat16*)W;  W += (size_t)NLAYER * DMODEL * RF * 2;
    __hip_bfloat16* wlm = (__hip_bfloat16*)W;  W += (size_t)VOCAB * DMODEL * 2;

    // batched weight conversion (one kernel)
    {
        CvtArgs a;
        a.s[0] = kqv_V;  a.d[0] = wkV;  a.n4[0] = (int)((size_t)NLAYER * NKQV * DMODEL / 4);
        a.s[1] = kqv_U;  a.d[1] = wkU;  a.n4[1] = (int)((size_t)NLAYER * 3 * NHEAD * HSZ * RH / 4);
        a.s[2] = proj_V; a.d[2] = wpV;  a.n4[2] = (int)((size_t)NLAYER * RP * DMODEL / 4);
        a.s[3] = proj_U; a.d[3] = wpU;  a.n4[3] = (int)((size_t)NLAYER * DMODEL * RP / 4);
        a.s[4] = f1_V;   a.d[4] = w1V;  a.n4[4] = (int)((size_t)NLAYER * RF * DMODEL / 4);
        a.s[5] = f1_U;   a.d[5] = w1U;  a.n4[5] = (int)((size_t)NLAYER * FFDIM * RF / 4);
        a.s[6] = f2_V;   a.d[6] = w2V;  a.n4[6] = (int)((size_t)NLAYER * RF * FFDIM / 4);
        a.s[7] = f2_U;   a.d[7] = w2U;  a.n4[7] = (int)((size_t)NLAYER * DMODEL * RF / 4);
        a.s[8] = lm_w;   a.d[8] = wlm;  a.n4[8] = (int)((size_t)VOCAB * DMODEL / 4);
        int total4 = 0;
        for (int k = 0; k < 9; ++k) total4 += a.n4[k];
        cvtall_k<<<dim3((total4 + 255) / 256), dim3(256), 0, stream>>>(a, total4);
    }

    embed_k<<<dim3(T_SEQ * DMODEL / 4 / 256), dim3(256), 0, stream>>>(idx, tok_emb, pos_emb, x);

    const int M = T_SEQ;
    for (int l = 0; l < NLAYER; ++l) {
        ln_k<<<dim3(T_SEQ), dim3(256), 0, stream>>>(x, ln1_w + l * DMODEL, ln1_b + l * DMODEL, hbuf);
        gemm_t<64, 64, 0><<<dim3((M / 64) * (NKQV / 64)), dim3(256), 0, stream>>>(
            hbuf, wkV + (size_t)l * NKQV * DMODEL, kqv_z + (size_t)l * NKQV,
            t1, nullptr, M, NKQV, DMODEL);
        kqv2_k<<<dim3(3 * NHEAD * T_SEQ * HSZ / 256), dim3(256), 0, stream>>>(
            t1, wkU + (size_t)l * 3 * NHEAD * HSZ * RH, qbuf, kb2, vt2);
        attn_k<<<dim3(T_SEQ / 64, NHEAD), dim3(256), 0, stream>>>(qbuf, kb2, vt2, attb);
        gemm_t<64, 64, 0><<<dim3((M / 64) * (RP / 64)), dim3(256), 0, stream>>>(
            attb, wpV + (size_t)l * RP * DMODEL, proj_z + (size_t)l * RP,
            t1, nullptr, M, RP, DMODEL);
        gemm_t<128, 128, 2><<<dim3((M / 128) * (DMODEL / 128)), dim3(256), 0, stream>>>(
            t1, wpU + (size_t)l * DMODEL * RP, nullptr,
            nullptr, x, M, DMODEL, RP);
        ln_k<<<dim3(T_SEQ), dim3(256), 0, stream>>>(x, ln2_w + l * DMODEL, ln2_b + l * DMODEL, hbuf);
        gemm_t<64, 64, 0><<<dim3((M / 64) * (RF / 64)), dim3(256), 0, stream>>>(
            hbuf, w1V + (size_t)l * RF * DMODEL, f1_z + (size_t)l * RF,
            t1, nullptr, M, RF, DMODEL);
        gemm_t<128, 128, 1><<<dim3((M / 128) * (FFDIM / 128)), dim3(256), 0, stream>>>(
            t1, w1U + (size_t)l * FFDIM * RF, nullptr,
            ffb, nullptr, M, FFDIM, RF);
        gemm_t<64, 64, 0><<<dim3((M / 64) * (RF / 64)), dim3(256), 0, stream>>>(
            ffb, w2V + (size_t)l * RF * FFDIM, f2_z + (size_t)l * RF,
            t1, nullptr, M, RF, FFDIM);
        gemm_t<128, 128, 2><<<dim3((M / 128) * (DMODEL / 128)), dim3(256), 0, stream>>>(
            t1, w2U + (size_t)l * DMODEL * RF, nullptr,
            nullptr, x, M, DMODEL, RF);
    }
    ln_k<<<dim3(T_SEQ), dim3(256), 0, stream>>>(x, lnf_w, lnf_b, hbuf);
    gemm_t<128, 128, 3><<<dim3((M / 128) * (VOCAB / 128)), dim3(256), 0, stream>>>(
        hbuf, wlm, nullptr, nullptr, (float*)d_out, M, VOCAB, DMODEL);
}

// Round 13
// 1161.109 us; speedup vs baseline: 1.1999x; 1.0140x over previous
//
#include <hip/hip_runtime.h>
#include <hip/hip_bf16.h>

// ---------------------------------------------------------------------------
// TransformerSquared forward on MI355X.
// R12 = R11 base + logits GEMM replaced by gemm256l: 256x256 tile, 8 waves,
// double-buffered LDS (128 KiB), counted vmcnt(8) pipeline (no drain in the
// main loop), verified unit-XOR swizzle at 128-B rows. All else unchanged.
// ---------------------------------------------------------------------------

#define T_SEQ 2048
#define DMODEL 1024
#define NHEAD 16
#define HSZ 64
#define NLAYER 4
#define FFDIM 4096
#define RH 16
#define RP 256
#define RF 256
#define VOCAB 32000
#define NKQV (3 * NHEAD * RH) // 768

typedef short short8 __attribute__((ext_vector_type(8)));
typedef float f32x4 __attribute__((ext_vector_type(4)));
typedef unsigned int uint_t;
typedef unsigned short ushort_t;

__device__ __forceinline__ float bfbits2f(uint_t bits16_in_low) {
    uint_t b = bits16_in_low << 16;
    float f;
    __builtin_memcpy(&f, &b, 4);
    return f;
}
__device__ __forceinline__ ushort_t f2bfu(float f) {
    union { __hip_bfloat16 b; ushort_t u; } cv;
    cv.b = __float2bfloat16(f);
    return cv.u;
}
__device__ __forceinline__ uint_t pack2bf(float a, float b) {
    return (uint_t)f2bfu(a) | ((uint_t)f2bfu(b) << 16);
}

// async global->LDS, 16 bytes per lane. LDS dest = wave-uniform base + lane*16.
__device__ __forceinline__ void gld16(const __hip_bfloat16* g, short* l) {
    __builtin_amdgcn_global_load_lds(
        (const __attribute__((address_space(1))) void*)g,
        (__attribute__((address_space(3))) void*)l, 16, 0, 0);
}

// ----------------------- batched f32 -> bf16 convert -----------------------
struct CvtArgs {
    const float* s[9];
    __hip_bfloat16* d[9];
    int n4[9];
};
__global__ __launch_bounds__(256) void cvtall_k(CvtArgs a, int total4) {
    int i = blockIdx.x * 256 + threadIdx.x;
    if (i >= total4) return;
#pragma unroll
    for (int k = 0; k < 9; ++k) {
        if (i < a.n4[k]) {
            float4 v = ((const float4*)a.s[k])[i];
            ushort4 o;
            o.x = f2bfu(v.x); o.y = f2bfu(v.y); o.z = f2bfu(v.z); o.w = f2bfu(v.w);
            ((ushort4*)a.d[k])[i] = o;
            return;
        }
        i -= a.n4[k];
    }
}

// ------------------------------- embedding ---------------------------------
__global__ __launch_bounds__(256) void embed_k(const int* __restrict__ idx,
                                               const float* __restrict__ tok,
                                               const float* __restrict__ pos,
                                               float* __restrict__ x) {
    int i = blockIdx.x * 256 + threadIdx.x;          // over T*D/4
    int d4 = i & (DMODEL / 4 - 1);
    int t = i >> 8;                                   // D/4 = 256
    int tk = idx[t];
    float4 a = ((const float4*)(tok + (size_t)tk * DMODEL))[d4];
    float4 p = ((const float4*)(pos + (size_t)t * DMODEL))[d4];
    a.x += p.x; a.y += p.y; a.z += p.z; a.w += p.w;
    ((float4*)(x + (size_t)t * DMODEL))[d4] = a;
}

// ------------------------------- layernorm ---------------------------------
__global__ __launch_bounds__(256) void ln_k(const float* __restrict__ xin,
                                            const float* __restrict__ w,
                                            const float* __restrict__ b,
                                            __hip_bfloat16* __restrict__ out) {
    const int row = blockIdx.x, tid = threadIdx.x;
    const float4 v = ((const float4*)(xin + (size_t)row * DMODEL))[tid];
    float s = v.x + v.y + v.z + v.w;
    float q = v.x * v.x + v.y * v.y + v.z * v.z + v.w * v.w;
    for (int off = 32; off; off >>= 1) { s += __shfl_xor(s, off); q += __shfl_xor(q, off); }
    __shared__ float rs_[4], rq_[4];
    if ((tid & 63) == 0) { rs_[tid >> 6] = s; rq_[tid >> 6] = q; }
    __syncthreads();
    s = rs_[0] + rs_[1] + rs_[2] + rs_[3];
    q = rq_[0] + rq_[1] + rq_[2] + rq_[3];
    const float mean = s * (1.f / DMODEL);
    const float var = q * (1.f / DMODEL) - mean * mean;
    const float rstd = rsqrtf(var + 1e-5f);
    const float4 wv = ((const float4*)w)[tid];
    const float4 bv = ((const float4*)b)[tid];
    ushort4 o;
    o.x = f2bfu((v.x - mean) * rstd * wv.x + bv.x);
    o.y = f2bfu((v.y - mean) * rstd * wv.y + bv.y);
    o.z = f2bfu((v.z - mean) * rstd * wv.z + bv.z);
    o.w = f2bfu((v.w - mean) * rstd * wv.w + bv.w);
    ((ushort4*)out)[(size_t)row * (DMODEL / 4) + tid] = o;
}

// --------------------------- generic GEMM (A * B^T) ------------------------
// m97-structure, 2-barrier, both-sides XOR swizzle (verified 0 conflicts R4).
template <int BM, int BN, int MODE>
__global__ __launch_bounds__(256) void gemm_t(const __hip_bfloat16* __restrict__ A,
                                              const __hip_bfloat16* __restrict__ B,
                                              const float* __restrict__ colscale,
                                              __hip_bfloat16* __restrict__ Cb,
                                              float* __restrict__ Cf,
                                              int M, int N, int K) {
    constexpr int WM = (BN >= 128) ? 2 : 4;
    constexpr int WN = 4 / WM;
    constexpr int TM = BM / WM / 16;
    constexpr int TN = BN / WN / 16;
    constexpr int IA = BM / 32;     // gld16 iters for A tile
    constexpr int IB = BN / 32;
    __shared__ short As[BM * 64];
    __shared__ short Bs[BN * 64];
    const int tid = threadIdx.x;
    const int w = tid >> 6, ln = tid & 63, lr = ln & 15, lg = ln >> 4;
    const int GM = M / BM;

    const int nwg = gridDim.x;
    const int cpx = nwg >> 3;
    const int wg = (blockIdx.x & 7) * cpx + (blockIdx.x >> 3);
    const int bm = wg % GM, bn = wg / GM;
    const int wm = w / WN, wn = w % WN;

    f32x4 acc[TM][TN] = {};

    const int srow = tid >> 3;
    const int scol = (((tid & 7) ^ ((tid >> 3) & 7)) * 8);
    const __hip_bfloat16* Ag = A + (size_t)(bm * BM + srow) * K + scol;
    const __hip_bfloat16* Bg = B + (size_t)(bn * BN + srow) * K + scol;

    for (int kt = 0; kt < K; kt += 64) {
        __syncthreads();   // previous tile consumed
#pragma unroll
        for (int i = 0; i < IA; ++i)
            gld16(Ag + (size_t)(i * 32) * K + kt, &As[i * 2048 + w * 512]);
#pragma unroll
        for (int i = 0; i < IB; ++i)
            gld16(Bg + (size_t)(i * 32) * K + kt, &Bs[i * 2048 + w * 512]);
        __syncthreads();   // drains vmcnt + barrier

#pragma unroll
        for (int kk = 0; kk < 2; ++kk) {
            short8 af[TM], bf[TN];
#pragma unroll
            for (int m = 0; m < TM; ++m) {
                const int row = wm * (BM / WM) + m * 16 + lr;
                af[m] = *(const short8*)&As[row * 64 + (((kk * 4 + lg) ^ (lr & 7)) * 8)];
            }
#pragma unroll
            for (int n = 0; n < TN; ++n) {
                const int row = wn * (BN / WN) + n * 16 + lr;
                bf[n] = *(const short8*)&Bs[row * 64 + (((kk * 4 + lg) ^ (lr & 7)) * 8)];
            }
#pragma unroll
            for (int m = 0; m < TM; ++m)
#pragma unroll
                for (int n = 0; n < TN; ++n)
                    acc[m][n] = __builtin_amdgcn_mfma_f32_16x16x32_bf16(af[m], bf[n], acc[m][n], 0, 0, 0);
        }
    }

#pragma unroll
    for (int n = 0; n < TN; ++n) {
        const int col = bn * BN + wn * (BN / WN) + n * 16 + lr;
        float cs = 1.0f;
        if (MODE == 0 && colscale) cs = colscale[col];
#pragma unroll
        for (int m = 0; m < TM; ++m) {
#pragma unroll
            for (int rr = 0; rr < 4; ++rr) {
                const int row = bm * BM + wm * (BM / WM) + m * 16 + lg * 4 + rr;
                float v = acc[m][n][rr];
                const size_t o = (size_t)row * N + col;
                if (MODE == 0) {
                    Cb[o] = __float2bfloat16(v * cs);
                } else if (MODE == 1) {
                    v = 0.5f * v * (1.0f + erff(v * 0.70710678118654752f));
                    Cb[o] = __float2bfloat16(v);
                } else if (MODE == 2) {
                    Cf[o] += v;
                } else {
                    Cf[o] = v;
                }
            }
        }
    }
}

// ---------------- logits GEMM: 256x256, counted-vmcnt pipeline -------------
// C[M,N] f32 = A[M,K] * B[N,K]^T. 512 thr = 8 waves (2 wm x 4 wn), wave tile
// 128x64. LDS: 2 buffers per operand (128 KiB). STAGE(t) = 8 gld16/wave.
// Main loop: vmcnt(8) (tile t+1 in flight) -> barrier -> ds_read kk0 ->
// MFMA kk0 overlap ds_read kk1 -> lgkmcnt(0) -> barrier -> STAGE(t+2) ->
// MFMA kk1. No vmcnt(0) drain except the final tile.
__global__ __launch_bounds__(512, 2) void gemm256l(const __hip_bfloat16* __restrict__ A,
                                                   const __hip_bfloat16* __restrict__ B,
                                                   float* __restrict__ C,
                                                   int M, int N, int K) {
    __shared__ short As[2][256 * 64];
    __shared__ short Bs[2][256 * 64];
    const int tid = threadIdx.x;
    const int w = tid >> 6, ln = tid & 63, lr = ln & 15, lg = ln >> 4;
    const int wm = w >> 2, wn = w & 3;
    const int GM = M / 256;              // 8

    const int nwg = gridDim.x;           // 1000
    const int cpx = nwg >> 3;            // 125
    const int wg = (blockIdx.x & 7) * cpx + (blockIdx.x >> 3);
    const int bm = wg % GM, bn = wg / GM;

    const int srow = tid >> 3;           // 0..63
    const int scol = (((tid & 7) ^ ((tid >> 3) & 7)) * 8);
    const __hip_bfloat16* Ag = A + (size_t)(bm * 256 + srow) * K + scol;
    const __hip_bfloat16* Bg = B + (size_t)(bn * 256 + srow) * K + scol;
    const int ldsb = w * 512;            // shorts; wave-uniform

    f32x4 acc[8][4] = {};

    auto STAGE = [&](int t) {
        const int b = t & 1;
        const size_t ko = (size_t)t * 64;
#pragma unroll
        for (int i = 0; i < 4; ++i) {
            gld16(Ag + (size_t)(i * 64) * K + ko, &As[b][i * 4096 + ldsb]);
            gld16(Bg + (size_t)(i * 64) * K + ko, &Bs[b][i * 4096 + ldsb]);
        }
    };

    STAGE(0); STAGE(1);                   // 16 vmem / wave outstanding

    const int T = K / 64;                 // 16
    for (int t = 0; t < T; ++t) {
        if (t < T - 1) asm volatile("s_waitcnt vmcnt(8)" ::: "memory");
        else           asm volatile("s_waitcnt vmcnt(0)" ::: "memory");
        __builtin_amdgcn_s_barrier();     // tile t present in buf[t&1]

        const short* Ab = As[t & 1];
        const short* Bb = Bs[t & 1];
        short8 af0[8], bf0[4], af1[8], bf1[4];
#pragma unroll
        for (int m = 0; m < 8; ++m) {
            const int R = wm * 128 + m * 16 + lr;
            af0[m] = *(const short8*)&Ab[R * 64 + ((lg ^ (lr & 7)) * 8)];
        }
#pragma unroll
        for (int n = 0; n < 4; ++n) {
            const int R = wn * 64 + n * 16 + lr;
            bf0[n] = *(const short8*)&Bb[R * 64 + ((lg ^ (lr & 7)) * 8)];
        }
        // kk0 MFMAs (compiler may overlap kk1 reads below with these)
#pragma unroll
        for (int m = 0; m < 8; ++m)
#pragma unroll
            for (int n = 0; n < 4; ++n)
                acc[m][n] = __builtin_amdgcn_mfma_f32_16x16x32_bf16(af0[m], bf0[n], acc[m][n], 0, 0, 0);
#pragma unroll
        for (int m = 0; m < 8; ++m) {
            const int R = wm * 128 + m * 16 + lr;
            af1[m] = *(const short8*)&Ab[R * 64 + (((4 + lg) ^ (lr & 7)) * 8)];
        }
#pragma unroll
        for (int n = 0; n < 4; ++n) {
            const int R = wn * 64 + n * 16 + lr;
            bf1[n] = *(const short8*)&Bb[R * 64 + (((4 + lg) ^ (lr & 7)) * 8)];
        }
        asm volatile("s_waitcnt lgkmcnt(0)" ::: "memory");
        __builtin_amdgcn_s_barrier();     // all waves done reading buf[t&1]
        if (t + 2 < T) STAGE(t + 2);      // overwrite buf[t&1] (safe)
        __builtin_amdgcn_sched_barrier(0);
        __builtin_amdgcn_s_setprio(1);
#pragma unroll
        for (int m = 0; m < 8; ++m)
#pragma unroll
            for (int n = 0; n < 4; ++n)
                acc[m][n] = __builtin_amdgcn_mfma_f32_16x16x32_bf16(af1[m], bf1[n], acc[m][n], 0, 0, 0);
        __builtin_amdgcn_s_setprio(0);
    }

#pragma unroll
    for (int m = 0; m < 8; ++m) {
        const int row = bm * 256 + wm * 128 + m * 16 + lg * 4;
#pragma unroll
        for (int rr = 0; rr < 4; ++rr) {
            float* crow = C + (size_t)(row + rr) * N + bn * 256 + wn * 64 + lr;
#pragma unroll
            for (int n = 0; n < 4; ++n)
                crow[n * 16] = acc[m][n][rr];
        }
    }
}

// ------------- per-head SVF U-projection (K=16) + layout fusion ------------
__global__ __launch_bounds__(256) void kqv2_k(const __hip_bfloat16* __restrict__ t1,
                                              const __hip_bfloat16* __restrict__ U,
                                              __hip_bfloat16* __restrict__ qb,
                                              __hip_bfloat16* __restrict__ kb2,
                                              __hip_bfloat16* __restrict__ vt2) {
    size_t i = (size_t)blockIdx.x * 256 + threadIdx.x; // 3*16*2048*64
    int s = (int)(i & 63);
    size_t rest = i >> 6;
    int t = (int)(rest & (T_SEQ - 1));
    int gh = (int)(rest >> 11);                        // 0..47, g-major
    const short8* trow = (const short8*)(t1 + (size_t)t * NKQV + gh * RH);
    const short8* urow = (const short8*)(U + ((size_t)gh * HSZ + s) * RH);
    short8 ta = trow[0], tb = trow[1];
    short8 ua = urow[0], ub = urow[1];
    float acc = 0.f;
#pragma unroll
    for (int j = 0; j < 8; ++j) {
        acc += bfbits2f((ushort_t)ta[j]) * bfbits2f((ushort_t)ua[j]);
        acc += bfbits2f((ushort_t)tb[j]) * bfbits2f((ushort_t)ub[j]);
    }
    const ushort_t val = f2bfu(acc);
    const int g = gh >> 4, h = gh & 15;               // block-uniform g
    if (g == 1) {
        ((ushort_t*)qb)[((size_t)h * T_SEQ + t) * HSZ + s] = val;
    } else if (g == 0) {
        const int tile = t >> 6, gg = (t >> 4) & 3, lr = t & 15;
        const int half = s >> 5, lg = (s >> 3) & 3, j = s & 7;
        const int c = gg * 2 + half, ln = lg * 16 + lr;
        ((ushort_t*)kb2)[(((size_t)h * 32 + tile) * 8 + c) * 512 + ln * 8 + j] = val;
    } else {
        const int tile = t >> 6, half = (t >> 5) & 1, lg2 = (t >> 3) & 3, j2 = t & 7;
        const int dt = s >> 4, lr2 = s & 15;
        const int c = dt * 2 + half, ln = lg2 * 16 + lr2;
        ((ushort_t*)vt2)[(((size_t)h * 32 + tile) * 8 + c) * 512 + ln * 8 + j2] = val;
    }
}

// --------------------------- MFMA flash attention --------------------------
__global__ __launch_bounds__(256) void attn_k(const __hip_bfloat16* __restrict__ qb,
                                              const __hip_bfloat16* __restrict__ kb2,
                                              const __hip_bfloat16* __restrict__ vt2,
                                              __hip_bfloat16* __restrict__ attout) {
    __shared__ short P_s[2][4][16 * 72];  // [dbuf][wave][16 q x 64 u], stride 72
    const int tid = threadIdx.x, w = tid >> 6, ln = tid & 63;
    const int lr = ln & 15, lg = ln >> 4;
    const int f = blockIdx.y * 32 + blockIdx.x;
    const int h = ((f & 7) << 1) | ((f >> 3) & 1);
    const int bi = f >> 4;
    const int t0 = bi * 16 + w * 512;
    const size_t hb = (size_t)h * T_SEQ;
    const size_t hB = (size_t)h * 32;   // tile base for chunk addressing
    const float SCL = 0.18033688011112042f; // 0.125 * log2(e)

    short8 qf0 = *(const short8*)(qb + (hb + t0 + lr) * HSZ + lg * 8);
    short8 qf1 = *(const short8*)(qb + (hb + t0 + lr) * HSZ + 32 + lg * 8);

    f32x4 acc[4] = {};
    float mrun = -3e38f, lrun = 0.f;
    int pbuf = 0;

    short8 kf[4][2];
#pragma unroll
    for (int g = 0; g < 4; ++g) {
        kf[g][0] = *(const short8*)(kb2 + (hB * 8 + g * 2 + 0) * 512 + (size_t)ln * 8);
        kf[g][1] = *(const short8*)(kb2 + (hB * 8 + g * 2 + 1) * 512 + (size_t)ln * 8);
    }

    for (int u0 = 0; u0 <= t0 + 15; u0 += 64) {
        const int it = u0 >> 6;
        f32x4 st[4];
#pragma unroll
        for (int g = 0; g < 4; ++g) {
            f32x4 z = {};
            z = __builtin_amdgcn_mfma_f32_16x16x32_bf16(kf[g][0], qf0, z, 0, 0, 0);
            st[g] = __builtin_amdgcn_mfma_f32_16x16x32_bf16(kf[g][1], qf1, z, 0, 0, 0);
        }

        const int un = u0 + 64;
        if (un <= t0 + 15) {
            const int itn = it + 1;
#pragma unroll
            for (int g = 0; g < 4; ++g) {
                kf[g][0] = *(const short8*)(kb2 + ((hB + itn) * 8 + g * 2 + 0) * 512 + (size_t)ln * 8);
                kf[g][1] = *(const short8*)(kb2 + ((hB + itn) * 8 + g * 2 + 1) * 512 + (size_t)ln * 8);
            }
        }
        short8 vf[4][2];
#pragma unroll
        for (int dt = 0; dt < 4; ++dt) {
            vf[dt][0] = *(const short8*)(vt2 + ((hB + it) * 8 + dt * 2 + 0) * 512 + (size_t)ln * 8);
            vf[dt][1] = *(const short8*)(vt2 + ((hB + it) * 8 + dt * 2 + 1) * 512 + (size_t)ln * 8);
        }

        const int qg = t0 + lr;
        float sv[16];
#pragma unroll
        for (int g = 0; g < 4; ++g) {
            const bool needm = (u0 + g * 16 + 15 > t0);
#pragma unroll
            for (int r = 0; r < 4; ++r) {
                float v = st[g][r] * SCL;
                if (needm && (u0 + g * 16 + lg * 4 + r > qg)) v = -1e30f;
                sv[g * 4 + r] = v;
            }
        }
        float tm = sv[0];
#pragma unroll
        for (int j = 1; j < 16; ++j) tm = fmaxf(tm, sv[j]);
        tm = fmaxf(tm, __shfl_xor(tm, 16));
        tm = fmaxf(tm, __shfl_xor(tm, 32));
        const float mnew = fmaxf(mrun, tm);
        const float corr = exp2f(mrun - mnew);
        float pv[16];
        float ls = 0.f;
#pragma unroll
        for (int j = 0; j < 16; ++j) { pv[j] = exp2f(sv[j] - mnew); ls += pv[j]; }
        ls += __shfl_xor(ls, 16);
        ls += __shfl_xor(ls, 32);
        lrun = lrun * corr + ls;
#pragma unroll
        for (int dt = 0; dt < 4; ++dt) acc[dt] *= corr;

        uint_t* pw = (uint_t*)P_s[pbuf][w];
        const int wb = lr * 36 + lg * 2;
#pragma unroll
        for (int g = 0; g < 4; ++g) {
            pw[wb + g * 8 + 0] = pack2bf(pv[g * 4 + 0], pv[g * 4 + 1]);
            pw[wb + g * 8 + 1] = pack2bf(pv[g * 4 + 2], pv[g * 4 + 3]);
        }
        asm volatile("s_waitcnt lgkmcnt(0)" ::: "memory");
        short8 pf0 = *(const short8*)(&P_s[pbuf][w][lr * 72 + lg * 8]);
        short8 pf1 = *(const short8*)(&P_s[pbuf][w][lr * 72 + 32 + lg * 8]);

#pragma unroll
        for (int dt = 0; dt < 4; ++dt) {
            acc[dt] = __builtin_amdgcn_mfma_f32_16x16x32_bf16(vf[dt][0], pf0, acc[dt], 0, 0, 0);
            acc[dt] = __builtin_amdgcn_mfma_f32_16x16x32_bf16(vf[dt][1], pf1, acc[dt], 0, 0, 0);
        }

        mrun = mnew;
        pbuf ^= 1;
    }

    const float inv = 1.f / lrun;
#pragma unroll
    for (int dt = 0; dt < 4; ++dt) {
#pragma unroll
        for (int r = 0; r < 4; r += 2) {
            uint_t pk = pack2bf(acc[dt][r] * inv, acc[dt][r + 1] * inv);
            *(uint_t*)(attout + (size_t)(t0 + lr) * DMODEL + h * HSZ + dt * 16 + lg * 4 + r) = pk;
        }
    }
}

// ---------------------------------------------------------------------------
extern "C" void kernel_launch(void* const* d_in, const int* in_sizes, int n_in,
                              void* d_out, int out_size, void* d_ws, size_t ws_size,
                              hipStream_t stream) {
    const int* idx = (const int*)d_in[0];
    const float* tok_emb = (const float*)d_in[1];
    const float* pos_emb = (const float*)d_in[2];
    const float* ln1_w = (const float*)d_in[3];
    const float* ln1_b = (const float*)d_in[4];
    const float* ln2_w = (const float*)d_in[5];
    const float* ln2_b = (const float*)d_in[6];
    const float* kqv_V = (const float*)d_in[7];
    const float* kqv_z = (const float*)d_in[8];
    const float* kqv_U = (const float*)d_in[9];
    const float* proj_V = (const float*)d_in[10];
    const float* proj_z = (const float*)d_in[11];
    const float* proj_U = (const float*)d_in[12];
    const float* f1_V = (const float*)d_in[13];
    const float* f1_z = (const float*)d_in[14];
    const float* f1_U = (const float*)d_in[15];
    const float* f2_V = (const float*)d_in[16];
    const float* f2_z = (const float*)d_in[17];
    const float* f2_U = (const float*)d_in[18];
    const float* lnf_w = (const float*)d_in[19];
    const float* lnf_b = (const float*)d_in[20];
    const float* lm_w = (const float*)d_in[21];

    // ---------------- workspace layout ----------------
    char* W = (char*)d_ws;
    float* x = (float*)W;                 W += (size_t)T_SEQ * DMODEL * 4;
    __hip_bfloat16* hbuf = (__hip_bfloat16*)W; W += (size_t)T_SEQ * DMODEL * 2;
    __hip_bfloat16* t1 = (__hip_bfloat16*)W;   W += (size_t)T_SEQ * NKQV * 2;
    __hip_bfloat16* qbuf = (__hip_bfloat16*)W; W += (size_t)NHEAD * T_SEQ * HSZ * 2;  // Q rows
    __hip_bfloat16* kb2 = (__hip_bfloat16*)W;  W += (size_t)NHEAD * T_SEQ * HSZ * 2;  // K chunk-tiled
    __hip_bfloat16* vt2 = (__hip_bfloat16*)W;  W += (size_t)NHEAD * HSZ * T_SEQ * 2;  // V^T chunk-tiled
    __hip_bfloat16* attb = (__hip_bfloat16*)W; W += (size_t)T_SEQ * DMODEL * 2;
    __hip_bfloat16* ffb = (__hip_bfloat16*)W;  W += (size_t)T_SEQ * FFDIM * 2;
    __hip_bfloat16* wkV = (__hip_bfloat16*)W;  W += (size_t)NLAYER * NKQV * DMODEL * 2;
    __hip_bfloat16* wkU = (__hip_bfloat16*)W;  W += (size_t)NLAYER * 3 * NHEAD * HSZ * RH * 2;
    __hip_bfloat16* wpV = (__hip_bfloat16*)W;  W += (size_t)NLAYER * RP * DMODEL * 2;
    __hip_bfloat16* wpU = (__hip_bfloat16*)W;  W += (size_t)NLAYER * DMODEL * RP * 2;
    __hip_bfloat16* w1V = (__hip_bfloat16*)W;  W += (size_t)NLAYER * RF * DMODEL * 2;
    __hip_bfloat16* w1U = (__hip_bfloat16*)W;  W += (size_t)NLAYER * FFDIM * RF * 2;
    __hip_bfloat16* w2V = (__hip_bfloat16*)W;  W += (size_t)NLAYER * RF * FFDIM * 2;
    __hip_bfloat16* w2U = (__hip_bfloat16*)W;  W += (size_t)NLAYER * DMODEL * RF * 2;
    __hip_bfloat16* wlm = (__hip_bfloat16*)W;  W += (size_t)VOCAB * DMODEL * 2;

    // batched weight conversion (one kernel)
    {
        CvtArgs a;
        a.s[0] = kqv_V;  a.d[0] = wkV;  a.n4[0] = (int)((size_t)NLAYER * NKQV * DMODEL / 4);
        a.s[1] = kqv_U;  a.d[1] = wkU;  a.n4[1] = (int)((size_t)NLAYER * 3 * NHEAD * HSZ * RH / 4);
        a.s[2] = proj_V; a.d[2] = wpV;  a.n4[2] = (int)((size_t)NLAYER * RP * DMODEL / 4);
        a.s[3] = proj_U; a.d[3] = wpU;  a.n4[3] = (int)((size_t)NLAYER * DMODEL * RP / 4);
        a.s[4] = f1_V;   a.d[4] = w1V;  a.n4[4] = (int)((size_t)NLAYER * RF * DMODEL / 4);
        a.s[5] = f1_U;   a.d[5] = w1U;  a.n4[5] = (int)((size_t)NLAYER * FFDIM * RF / 4);
        a.s[6] = f2_V;   a.d[6] = w2V;  a.n4[6] = (int)((size_t)NLAYER * RF * FFDIM / 4);
        a.s[7] = f2_U;   a.d[7] = w2U;  a.n4[7] = (int)((size_t)NLAYER * DMODEL * RF / 4);
        a.s[8] = lm_w;   a.d[8] = wlm;  a.n4[8] = (int)((size_t)VOCAB * DMODEL / 4);
        int total4 = 0;
        for (int k = 0; k < 9; ++k) total4 += a.n4[k];
        cvtall_k<<<dim3((total4 + 255) / 256), dim3(256), 0, stream>>>(a, total4);
    }

    embed_k<<<dim3(T_SEQ * DMODEL / 4 / 256), dim3(256), 0, stream>>>(idx, tok_emb, pos_emb, x);

    const int M = T_SEQ;
    for (int l = 0; l < NLAYER; ++l) {
        ln_k<<<dim3(T_SEQ), dim3(256), 0, stream>>>(x, ln1_w + l * DMODEL, ln1_b + l * DMODEL, hbuf);
        gemm_t<64, 64, 0><<<dim3((M / 64) * (NKQV / 64)), dim3(256), 0, stream>>>(
            hbuf, wkV + (size_t)l * NKQV * DMODEL, kqv_z + (size_t)l * NKQV,
            t1, nullptr, M, NKQV, DMODEL);
        kqv2_k<<<dim3(3 * NHEAD * T_SEQ * HSZ / 256), dim3(256), 0, stream>>>(
            t1, wkU + (size_t)l * 3 * NHEAD * HSZ * RH, qbuf, kb2, vt2);
        attn_k<<<dim3(T_SEQ / 64, NHEAD), dim3(256), 0, stream>>>(qbuf, kb2, vt2, attb);
        gemm_t<64, 64, 0><<<dim3((M / 64) * (RP / 64)), dim3(256), 0, stream>>>(
            attb, wpV + (size_t)l * RP * DMODEL, proj_z + (size_t)l * RP,
            t1, nullptr, M, RP, DMODEL);
        gemm_t<128, 128, 2><<<dim3((M / 128) * (DMODEL / 128)), dim3(256), 0, stream>>>(
            t1, wpU + (size_t)l * DMODEL * RP, nullptr,
            nullptr, x, M, DMODEL, RP);
        ln_k<<<dim3(T_SEQ), dim3(256), 0, stream>>>(x, ln2_w + l * DMODEL, ln2_b + l * DMODEL, hbuf);
        gemm_t<64, 64, 0><<<dim3((M / 64) * (RF / 64)), dim3(256), 0, stream>>>(
            hbuf, w1V + (size_t)l * RF * DMODEL, f1_z + (size_t)l * RF,
            t1, nullptr, M, RF, DMODEL);
        gemm_t<128, 128, 1><<<dim3((M / 128) * (FFDIM / 128)), dim3(256), 0, stream>>>(
            t1, w1U + (size_t)l * FFDIM * RF, nullptr,
            ffb, nullptr, M, FFDIM, RF);
        gemm_t<64, 64, 0><<<dim3((M / 64) * (RF / 64)), dim3(256), 0, stream>>>(
            ffb, w2V + (size_t)l * RF * FFDIM, f2_z + (size_t)l * RF,
            t1, nullptr, M, RF, FFDIM);
        gemm_t<128, 128, 2><<<dim3((M / 128) * (DMODEL / 128)), dim3(256), 0, stream>>>(
            t1, w2U + (size_t)l * DMODEL * RF, nullptr,
            nullptr, x, M, DMODEL, RF);
    }
    ln_k<<<dim3(T_SEQ), dim3(256), 0, stream>>>(x, lnf_w, lnf_b, hbuf);
    // logits: 256x256 counted-vmcnt pipeline, grid 8*125 = 1000 (div by 8)
    gemm256l<<<dim3((M / 256) * (VOCAB / 256)), dim3(512), 0, stream>>>(
        hbuf, wlm, (float*)d_out, M, VOCAB, DMODEL);
}